// Round 10
// baseline (2787.216 us; speedup 1.0000x reference)
//
#include <hip/hip_runtime.h>
#include <hip/hip_bf16.h>

// Problem constants
#define B_   4096
#define T_   60
#define TT   30          // pooled sequence length
#define H_   512
#define L_   2
#define NH_  4
#define DH_  128
#define LAT_ 128
#define OUT_ 14
#define NGATE_ (5*H_)    // 2560
#define EPSF 1e-5f
#define FEATK 64         // feat padded to 64 (GEMM K granularity)
#define K0M  (FEATK + H_)   // 576: layer0 merged K (composed feat + h)

typedef __attribute__((ext_vector_type(8))) short bf16x8;
typedef __attribute__((ext_vector_type(4))) short bf16x4;
typedef __attribute__((ext_vector_type(4))) float f32x4;

__device__ __forceinline__ float sigmoidf_(float x) { return 1.0f / (1.0f + __expf(-x)); }
__device__ __forceinline__ float bf2f(short s) {
    return __uint_as_float(((unsigned)(unsigned short)s) << 16);
}

__device__ __forceinline__ void async_load16(const void* g, void* l) {
    __builtin_amdgcn_global_load_lds((const __attribute__((address_space(1))) void*)g,
                                     (__attribute__((address_space(3))) void*)l, 16, 0, 0);
}

// Gate-row permutation: original n = g*512 + j  ->  n' = (j>>4)*80 + g*16 + (j&15).
__device__ __forceinline__ int perm_row(int n) {
    int g = n >> 9, j = n & 511;
    return (j >> 4) * 80 + g * 16 + (j & 15);
}

// ---------------------------------------------------------------------------
// Utility kernels
// ---------------------------------------------------------------------------
__global__ __launch_bounds__(256) void cvt_bf16(const float* __restrict__ in,
                                                __hip_bfloat16* __restrict__ out, long n) {
    long i = (long)blockIdx.x * blockDim.x + threadIdx.x;
    long stride = (long)gridDim.x * blockDim.x;
    for (; i < n; i += stride) out[i] = __float2bfloat16(in[i]);
}

__global__ __launch_bounds__(256) void zero_f32(float* __restrict__ p, long n) {
    long i = (long)blockIdx.x * blockDim.x + threadIdx.x;
    long stride = (long)gridDim.x * blockDim.x;
    for (; i < n; i += stride) p[i] = 0.0f;
}

// layer1 gate weights f32 -> bf16, rows permuted for the fused kernel
__global__ __launch_bounds__(256)
void perm_w1(const float* __restrict__ gw, __hip_bfloat16* __restrict__ w1p) {
    long i = (long)blockIdx.x * 256 + threadIdx.x;       // 2560*1024
    if (i >= (long)NGATE_ * 2 * H_) return;
    int n = (int)(i >> 10), k = (int)(i & 1023);
    w1p[(long)perm_row(n) * (2 * H_) + k] = __float2bfloat16(gw[i]);
}

// Compose proj into layer0's input weights; rows permuted.
__global__ __launch_bounds__(256)
void build_w0m(const float* __restrict__ gw, const float* __restrict__ pw,
               const float* __restrict__ pb, const float* __restrict__ gb,
               __hip_bfloat16* __restrict__ w0p, float* __restrict__ bc) {
    const int tid = threadIdx.x;
    const int n = blockIdx.x * 4 + (tid >> 6);   // 640 blocks * 4 = 2560 rows
    const int f = tid & 63;
    const long np = perm_row(n);
    const float* wrow = gw + (long)n * (2 * H_);  // layer0 gate row [1024]
    float acc = 0.f;
    if (f < 44) {
        for (int k = 0; k < H_; ++k) acc += wrow[k] * pw[k * 44 + f];
    }
    w0p[np * K0M + f] = __float2bfloat16(acc);
    #pragma unroll
    for (int j = 0; j < 8; ++j) {
        int col = f * 8 + j;
        w0p[np * K0M + FEATK + col] = __float2bfloat16(wrow[H_ + col]);
    }
    float s = 0.f;
    #pragma unroll
    for (int j = 0; j < 8; ++j) s += wrow[f * 8 + j] * pb[f * 8 + j];
    #pragma unroll
    for (int off = 32; off > 0; off >>= 1) s += __shfl_down(s, off, 64);
    if (f == 0) bc[n] = gb[n] + s;
}

// Block-diagonal W_k^T for attention (unchanged)
__global__ __launch_bounds__(256)
void build_wkd(const float* __restrict__ aiw, __hip_bfloat16* __restrict__ wkd) {
    int i = blockIdx.x * 256 + threadIdx.x;          // 2048*512
    if (i >= 2048 * 512) return;
    int n = i >> 9, k = i & 511;
    float v = ((k >> 7) == (n >> 9)) ? aiw[(H_ + k) * H_ + (n & 511)] : 0.f;
    wkd[i] = __float2bfloat16(v);
}

__global__ __launch_bounds__(256)
void build_wvd(const float* __restrict__ aiw, __hip_bfloat16* __restrict__ wvd) {
    int i = blockIdx.x * 256 + threadIdx.x;          // 512*2048
    if (i >= 512 * 2048) return;
    int n = i >> 11, k = i & 2047;
    float v = ((k >> 9) == (n >> 7)) ? aiw[(2 * H_ + n) * H_ + (k & 511)] : 0.f;
    wvd[i] = __float2bfloat16(v);
}

// ---------------------------------------------------------------------------
// Front-end (unchanged)
// ---------------------------------------------------------------------------
__global__ __launch_bounds__(256)
void frontend_kernel(const float* __restrict__ x,
                     const float* __restrict__ cw, const float* __restrict__ cb,
                     const float* __restrict__ bg, const float* __restrict__ bb,
                     const float* __restrict__ brm, const float* __restrict__ brv,
                     const float* __restrict__ compw, const float* __restrict__ compb,
                     __hip_bfloat16* __restrict__ feat_out) {
    const int b = blockIdx.x, tid = threadIdx.x;
    __shared__ float xs[T_ * 17];
    __shared__ float ybuf[24][T_];
    __shared__ float feat[TT][44];

    for (int i = tid; i < T_ * 17; i += 256) xs[i] = x[(long)b * T_ * 17 + i];
    __syncthreads();

    for (int i = tid; i < 24 * T_; i += 256) {
        int oc = i / T_, t = i % T_;
        float acc = cb[oc];
        #pragma unroll
        for (int kk = 0; kk < 3; ++kk) {
            int tt = t + kk - 1;
            if (tt >= 0 && tt < T_) {
                #pragma unroll
                for (int ic = 0; ic < 9; ++ic)
                    acc += xs[tt * 17 + ic] * cw[(oc * 9 + ic) * 3 + kk];
            }
        }
        acc = fmaxf(acc, 0.f);
        acc = (acc - brm[oc]) * rsqrtf(brv[oc] + EPSF) * bg[oc] + bb[oc];
        ybuf[oc][t] = acc;
    }
    __syncthreads();

    for (int i = tid; i < TT * 24; i += 256) {
        int u = i / 24, oc = i % 24;
        feat[u][oc] = fmaxf(ybuf[oc][2 * u], ybuf[oc][2 * u + 1]);
    }
    for (int i = tid; i < TT * 20; i += 256) {
        int u = i / 20, oc = i % 20;
        float acc = compb[oc];
        #pragma unroll
        for (int j = 0; j < 8; ++j) acc += xs[u * 17 + 9 + j] * compw[oc * 8 + j];
        feat[u][24 + oc] = fmaxf(acc, 0.f);
    }
    __syncthreads();

    for (int i = tid; i < TT * FEATK; i += 256) {
        int u = i >> 6, c = i & 63;
        float v = (c < 44) ? feat[u][c] : 0.f;
        feat_out[((long)b * TT + u) * FEATK + c] = __float2bfloat16(v);
    }
}

// ---------------------------------------------------------------------------
// bf16 MFMA GEMM core (BK=64, proven) — kept for the attention chain.
// ---------------------------------------------------------------------------
template <int WRITE_BF16>
__device__ __forceinline__
void gemm_core(const __hip_bfloat16* __restrict__ A0, int lda0,
               const __hip_bfloat16* __restrict__ A1, int lda1, int ksplit,
               const __hip_bfloat16* __restrict__ W, int ldw,
               const float* __restrict__ bias,
               void* __restrict__ Cout, int ldc, int K, int bx, int by) {
    __shared__ __hip_bfloat16 As[128 * 64];
    __shared__ __hip_bfloat16 Bs[128 * 64];
    const int tid = threadIdx.x;
    const int wave = tid >> 6, lane = tid & 63;
    const long m0 = (long)by * 128;
    const long n0 = (long)bx * 128;

    f32x4 acc[4][4] = {};

    for (int k0 = 0; k0 < K; k0 += 64) {
        __syncthreads();
        #pragma unroll
        for (int it = 0; it < 4; ++it) {
            int id = it * 256 + tid;
            int row = id >> 3;
            int kc = ((id & 7) ^ (row & 7)) << 3;
            int gk = k0 + kc;
            const __hip_bfloat16* srcA;
            if (gk < ksplit) srcA = A0 + (m0 + row) * (long)lda0 + gk;
            else             srcA = A1 + (m0 + row) * (long)lda1 + (gk - ksplit);
            async_load16(srcA, &As[id * 8]);
            const __hip_bfloat16* srcB = W + (n0 + row) * (long)ldw + gk;
            async_load16(srcB, &Bs[id * 8]);
        }
        __syncthreads();
        #pragma unroll
        for (int ks = 0; ks < 2; ++ks) {
            const int kb = ((ks * 4 + (lane >> 4)) ^ (lane & 7)) << 3;
            const int ar = (wave >> 1) * 64 + (lane & 15);
            const int br = (wave & 1) * 64 + (lane & 15);
            bf16x8 afr[4], bfr[4];
            #pragma unroll
            for (int i = 0; i < 4; ++i) afr[i] = *(const bf16x8*)&As[(ar + i * 16) * 64 + kb];
            #pragma unroll
            for (int i = 0; i < 4; ++i) bfr[i] = *(const bf16x8*)&Bs[(br + i * 16) * 64 + kb];
            #pragma unroll
            for (int mi = 0; mi < 4; ++mi)
                #pragma unroll
                for (int ni = 0; ni < 4; ++ni)
                    acc[mi][ni] = __builtin_amdgcn_mfma_f32_16x16x32_bf16(afr[mi], bfr[ni], acc[mi][ni], 0, 0, 0);
        }
    }

    const int cr = (lane >> 4) * 4;
    const int ccol = lane & 15;
    #pragma unroll
    for (int ni = 0; ni < 4; ++ni) {
        long col = n0 + (wave & 1) * 64 + ni * 16 + ccol;
        float bv = bias ? bias[col] : 0.f;
        #pragma unroll
        for (int mi = 0; mi < 4; ++mi) {
            long rowb = m0 + (wave >> 1) * 64 + mi * 16 + cr;
            #pragma unroll
            for (int r = 0; r < 4; ++r) {
                float v = acc[mi][ni][r] + bv;
                if (WRITE_BF16)
                    ((__hip_bfloat16*)Cout)[(rowb + r) * (long)ldc + col] = __float2bfloat16(v);
                else
                    ((float*)Cout)[(rowb + r) * (long)ldc + col] = v;
            }
        }
    }
}

template <int WRITE_BF16>
__global__ __launch_bounds__(256)
void gemm_bias(const __hip_bfloat16* __restrict__ A0, int lda0,
               const __hip_bfloat16* __restrict__ A1, int lda1, int ksplit,
               const __hip_bfloat16* __restrict__ W, int ldw,
               const float* __restrict__ bias,
               void* __restrict__ Cout, int ldc, int K) {
    gemm_core<WRITE_BF16>(A0, lda0, A1, lda1, ksplit, W, ldw, bias, Cout, ldc, K,
                          blockIdx.x, blockIdx.y);
}

// ---------------------------------------------------------------------------
// R20 fused gate GEMM: occupancy-first hybrid.
//  - W (cross-block-reused operand) stays in LDS, double-buffered, staged via
//    global_load_lds with the R19 hoisted it-invariant swizzle (proven).
//  - A (zero cross-wave reuse: each wave reads only its own 32 rows) is
//    loaded DIRECTLY into registers per-lane (R17-proven fragment layout:
//    lane l -> row (l&15)+mi*16, k = kk*64 + ks*32 + (l>>4)*8; lanes
//    {l,l+16,l+32,l+48} cover one 64B line).
//  LDS 52 KB -> 20 KB: blocks/CU jump 3 -> ~7 (VGPR-capped ~4-5 waves/SIMD),
//  doubling resident waves so TLP hides the per-slab barrier drain that kept
//  all pipes <30% through R14-R19. Staging: 7 -> 3 async-loads per slab.
//  Epilogue/f32 handoff identical to R14..R19 (absmax 0.0042 proven).
// ---------------------------------------------------------------------------
__device__ __forceinline__
void fused_gate_core(const __hip_bfloat16* __restrict__ A0, int lda0,
                     const __hip_bfloat16* __restrict__ A1, int lda1,
                     int ksplit, int K,
                     const __hip_bfloat16* __restrict__ Wp, int ldw,
                     const float* __restrict__ bias,
                     const float* __restrict__ ret,
                     float* __restrict__ c_t,
                     float* __restrict__ opre,
                     float* __restrict__ tcn,
                     int m, int nblk) {
    __shared__ __hip_bfloat16 Bs[2][80 * 64];
    const int tid = threadIdx.x;
    const int wave = tid >> 6, lane = tid & 63;
    const long m0 = (long)m * 128;
    const int n0row = nblk * 80;
    const int jbase = nblk * 16;
    const int rsel = lane & 15;
    const int q = lane >> 4;

    // W staging addresses (hoisted, it-invariant swizzle) — identical to R19.
    const int kc = ((tid & 7) ^ ((tid >> 3) & 7)) << 3;
    const int srow = tid >> 3;                       // 0..31
    const __hip_bfloat16* pB_t = Wp + (long)(n0row + srow) * ldw + kc;

    // Direct per-lane A fragment pointers (R17-proven layout).
    const long arow = m0 + wave * 32 + rsel;
    const __hip_bfloat16* pa0 = A0 + arow * (long)lda0 + q * 8;
    const __hip_bfloat16* pa1 =
        A1 ? (A1 + arow * (long)lda1 + q * 8 - ksplit) : pa0;
    const long a0s16 = (long)16 * lda0;              // mi stride (rows)
    const long a1s16 = (long)16 * lda1;

    const int ks_slab = ksplit >> 6;
    const int nslab = K >> 6;

    auto stage = [&](int hb, int kk) {
        const long koff = (long)kk << 6;
        #pragma unroll
        for (int it = 0; it < 2; ++it)
            async_load16(pB_t + (long)it * 32 * ldw + koff,
                         &Bs[hb][it * 2048 + tid * 8]);
        if (tid < 128)
            async_load16(pB_t + (long)64 * ldw + koff,
                         &Bs[hb][4096 + tid * 8]);
    };

    stage(0, 0);
    f32x4 acc[2][5] = {};

    for (int kk = 0; kk < nslab; ++kk) {
        const int hb = kk & 1;
        __syncthreads();
        if (kk + 1 < nslab) stage(hb ^ 1, kk + 1);
        // A fragments for this slab: direct global -> registers.
        const __hip_bfloat16* pa;
        long as16;
        if (kk < ks_slab) { pa = pa0 + ((long)kk << 6); as16 = a0s16; }
        else              { pa = pa1 + ((long)kk << 6); as16 = a1s16; }
        bf16x8 a_[2][2];
        #pragma unroll
        for (int mi = 0; mi < 2; ++mi)
            #pragma unroll
            for (int ks = 0; ks < 2; ++ks)
                a_[mi][ks] = *(const bf16x8*)(pa + mi * as16 + ks * 32);
        #pragma unroll
        for (int ks = 0; ks < 2; ++ks) {
            const int kb = ((ks * 4 + q) ^ (lane & 7)) << 3;
            bf16x8 bfr[5];
            #pragma unroll
            for (int i = 0; i < 5; ++i)
                bfr[i] = *(const bf16x8*)&Bs[hb][(i * 16 + rsel) * 64 + kb];
            #pragma unroll
            for (int mi = 0; mi < 2; ++mi)
                #pragma unroll
                for (int ni = 0; ni < 5; ++ni)
                    acc[mi][ni] = __builtin_amdgcn_mfma_f32_16x16x32_bf16(bfr[ni], a_[mi][ks], acc[mi][ni], 0, 0, 0);
        }
    }

    // Fused epilogue: per thread 2 b-rows x 4 j, full gate quintuple in-register.
    #pragma unroll
    for (int mi = 0; mi < 2; ++mi) {
        const long b = m0 + wave * 32 + mi * 16 + rsel;
        f32x4 ov, tv;
        #pragma unroll
        for (int r = 0; r < 4; ++r) {
            const int jg = jbase + 4 * q + r;
            float f  = sigmoidf_(acc[mi][0][r] + bias[jg]);
            float ii = sigmoidf_(acc[mi][1][r] + bias[512 + jg]);
            float o  = sigmoidf_(acc[mi][2][r] + bias[1024 + jg]);
            float cc = tanhf(acc[mi][3][r] + bias[1536 + jg]);
            float mg = sigmoidf_(acc[mi][4][r] + bias[2048 + jg]);
            float cold = c_t[(long)jg * B_ + b];
            float rr = ret[jg];
            float cn = f * cold + ii * cc;
            cn = cn * rr + (1.f - rr) * cold;
            cn = mg * cn + (1.f - mg) * cold;
            c_t[(long)jg * B_ + b] = cn;
            ov[r] = o;
            tv[r] = tanhf(cn);
        }
        *(f32x4*)&opre[b * H_ + jbase + 4 * q] = ov;
        *(f32x4*)&tcn [b * H_ + jbase + 4 * q] = tv;
    }
}

// Single-layer wrapper (boundary steps). grid = 1024 (32 m x 32 n), XCD-grouped.
__global__ __launch_bounds__(256, 4)
void fused_gate_single(const __hip_bfloat16* A0, int lda0, const __hip_bfloat16* A1,
                       int lda1, int ksplit, int K,
                       const __hip_bfloat16* Wp, int ldw,
                       const float* bias, const float* ret, float* c_t,
                       float* opre, float* tcn) {
    const int id = blockIdx.x;
    const int xcd = id & 7;
    const int rest = id >> 3;                 // [0,128)
    const int m = xcd * 4 + (rest & 3);
    const int n = (rest >> 2) & 31;
    fused_gate_core(A0, lda0, A1, lda1, ksplit, K, Wp, ldw, bias, ret, c_t,
                    opre, tcn, m, n);
}

// Dual-layer wrapper. grid = 2048: xcd=id&7; rest bits [0:1]=m-sub, [2:6]=n, [7]=z.
__global__ __launch_bounds__(256, 4)
void fused_gate_dual(const __hip_bfloat16* A0a, int lda0a, const __hip_bfloat16* A1a,
                     int lda1a, int ksplita, int Ka,
                     const __hip_bfloat16* Wpa, int ldwa,
                     const float* biasa, const float* reta, float* cta,
                     float* oprea, float* tcna,
                     const __hip_bfloat16* A0b, int lda0b, const __hip_bfloat16* A1b,
                     int lda1b, int ksplitb, int Kb,
                     const __hip_bfloat16* Wpb, int ldwb,
                     const float* biasb, const float* retb, float* ctb,
                     float* opreb, float* tcnb) {
    const int id = blockIdx.x;
    const int xcd = id & 7;
    const int rest = id >> 3;                 // [0,256)
    const int m = xcd * 4 + (rest & 3);
    const int n = (rest >> 2) & 31;
    const int z = rest >> 7;
    if (z == 0)
        fused_gate_core(A0a, lda0a, A1a, lda1a, ksplita, Ka, Wpa, ldwa,
                        biasa, reta, cta, oprea, tcna, m, n);
    else
        fused_gate_core(A0b, lda0b, A1b, lda1b, ksplitb, Kb, Wpb, ldwb,
                        biasb, retb, ctb, opreb, tcnb, m, n);
}

// ---------------------------------------------------------------------------
// gate_ln: the two LayerNorms (need full-j stats) on f32 o/tanh(c).
// ---------------------------------------------------------------------------
__device__ __forceinline__ void block_reduce2(float& a, float& b, float* red) {
    #pragma unroll
    for (int off = 32; off > 0; off >>= 1) {
        a += __shfl_down(a, off, 64);
        b += __shfl_down(b, off, 64);
    }
    int lane = threadIdx.x & 63, w = threadIdx.x >> 6;
    if (lane == 0) { red[w] = a; red[8 + w] = b; }
    __syncthreads();
    a = red[0] + red[1] + red[2] + red[3];
    b = red[8] + red[9] + red[10] + red[11];
    __syncthreads();
}

__device__ __forceinline__
void gate_ln_body(const float* __restrict__ opre,
                  const float* __restrict__ tcn,
                  const float* __restrict__ elg, const float* __restrict__ elb,
                  const float* __restrict__ lng, const float* __restrict__ lnb,
                  __hip_bfloat16* __restrict__ hout, long hstride, int b) {
    const int tid = threadIdx.x;
    __shared__ float red[16];

    float o_[2], t_[2];
    float s = 0.f, s2 = 0.f;
    #pragma unroll
    for (int u = 0; u < 2; ++u) {
        int j = tid + u * 256;
        float o = opre[(long)b * H_ + j];
        float t = tcn[(long)b * H_ + j];
        o_[u] = o; t_[u] = t;
        s += o; s2 += o * o;
    }
    block_reduce2(s, s2, red);
    float mean = s * (1.f / H_);
    float var = s2 * (1.f / H_) - mean * mean;
    float rstd = rsqrtf(var + EPSF);

    float val[2];
    float s3 = 0.f, s4 = 0.f;
    #pragma unroll
    for (int u = 0; u < 2; ++u) {
        int j = tid + u * 256;
        float on = (o_[u] - mean) * rstd * elg[j] + elb[j];
        float v = sigmoidf_(on) * t_[u];
        val[u] = v; s3 += v; s4 += v * v;
    }
    block_reduce2(s3, s4, red);
    float mean2 = s3 * (1.f / H_);
    float var2 = s4 * (1.f / H_) - mean2 * mean2;
    float rstd2 = rsqrtf(var2 + EPSF);
    #pragma unroll
    for (int u = 0; u < 2; ++u) {
        int j = tid + u * 256;
        float h = (val[u] - mean2) * rstd2 * lng[j] + lnb[j];
        hout[(long)b * hstride + j] = __float2bfloat16(h);
    }
}

__global__ __launch_bounds__(256)
void gate_ln(const float* __restrict__ opre,
             const float* __restrict__ tcn,
             const float* __restrict__ elg, const float* __restrict__ elb,
             const float* __restrict__ lng, const float* __restrict__ lnb,
             __hip_bfloat16* __restrict__ hout, long hstride) {
    gate_ln_body(opre, tcn, elg, elb, lng, lnb, hout, hstride, blockIdx.x);
}

__global__ __launch_bounds__(256)
void gate_ln_dual(const float* oa, const float* ta,
                  const float* elga, const float* elba,
                  const float* lnga, const float* lnba,
                  __hip_bfloat16* houta, long hstridea,
                  const float* ob, const float* tb,
                  const float* elgb, const float* elbb,
                  const float* lngb, const float* lnbb,
                  __hip_bfloat16* houtb, long hstrideb) {
    int bid = blockIdx.x;
    bool isB = bid >= B_;
    int b = isB ? bid - B_ : bid;
    gate_ln_body(isB ? ob : oa, isB ? tb : ta,
                 isB ? elgb : elga, isB ? elbb : elba,
                 isB ? lngb : lnga, isB ? lnbb : lnba,
                 isB ? houtb : houta, isB ? hstrideb : hstridea, b);
}

// ---------------------------------------------------------------------------
// R11 fused attention (unchanged).
// ---------------------------------------------------------------------------
__global__ __launch_bounds__(256)
void attn_fused(const __hip_bfloat16* __restrict__ seq,
                const __hip_bfloat16* __restrict__ U,
                __hip_bfloat16* __restrict__ sbar) {
    const int b = blockIdx.x, tid = threadIdx.x;
    const int h = tid >> 6, lane = tid & 63;
    const int c0 = lane * 8;
    __shared__ float ps[NH_ * TT];      // 480 B
    const float scale = 0.08838834764831845f;   // 1/sqrt(128)

    float uq[8];
    {
        bf16x8 uv = *(const bf16x8*)&U[(size_t)b * (NH_ * H_) + h * H_ + c0];
        for (int j = 0; j < 8; ++j) uq[j] = bf2f(uv[j]);
    }
    const __hip_bfloat16* srow = seq + (size_t)b * TT * H_;

    for (int t = 0; t < TT; ++t) {
        bf16x8 sv = *(const bf16x8*)&srow[t * H_ + c0];
        float a = 0.f;
        for (int j = 0; j < 8; ++j) a += uq[j] * bf2f(sv[j]);
        a += __shfl_xor(a, 32);
        a += __shfl_xor(a, 16);
        a += __shfl_xor(a, 8);
        a += __shfl_xor(a, 4);
        a += __shfl_xor(a, 2);
        a += __shfl_xor(a, 1);
        if (lane == 0) ps[h * TT + t] = a * scale;
    }
    __syncthreads();

    float mx = -1e30f;
    for (int t = 0; t < TT; ++t) mx = fmaxf(mx, ps[h * TT + t]);
    float den = 0.f;
    for (int t = 0; t < TT; ++t) den += __expf(ps[h * TT + t] - mx);
    float inv = 1.f / den;

    float accv[8];
    for (int j = 0; j < 8; ++j) accv[j] = 0.f;
    for (int t = 0; t < TT; ++t) {
        float w = __expf(ps[h * TT + t] - mx) * inv;
        bf16x8 sv = *(const bf16x8*)&srow[t * H_ + c0];
        for (int j = 0; j < 8; ++j) accv[j] += w * bf2f(sv[j]);
    }
    bf16x8 outv;
    for (int j = 0; j < 8; ++j) {
        __hip_bfloat16 hv = __float2bfloat16(accv[j]);
        outv[j] = *(short*)&hv;
    }
    *(bf16x8*)&sbar[(size_t)b * (NH_ * H_) + h * H_ + c0] = outv;
}

// ---------------------------------------------------------------------------
// Head (unchanged).
// ---------------------------------------------------------------------------
__global__ __launch_bounds__(128)
void head_kernel(const float* __restrict__ lat_in,
                 const float* __restrict__ g2, const float* __restrict__ b2,
                 const float* __restrict__ rm2, const float* __restrict__ rv2,
                 const float* __restrict__ ow, const float* __restrict__ ob,
                 float* __restrict__ out) {
    const int b = blockIdx.x, tid = threadIdx.x;
    __shared__ float ls[LAT_];
    float a = lat_in[(long)b * LAT_ + tid];
    ls[tid] = (a - rm2[tid]) * rsqrtf(rv2[tid] + EPSF) * g2[tid] + b2[tid];
    __syncthreads();
    if (tid < OUT_) {
        float acc = ob[tid];
        #pragma unroll 4
        for (int j = 0; j < LAT_; ++j) acc += ls[j] * ow[tid * LAT_ + j];
        out[(long)b * OUT_ + tid] = acc;
    }
}

// ---------------------------------------------------------------------------
extern "C" void kernel_launch(void* const* d_in, const int* in_sizes, int n_in,
                              void* d_out, int out_size, void* d_ws, size_t ws_size,
                              hipStream_t stream) {
    const float* x        = (const float*)d_in[0];
    const float* conv1_w  = (const float*)d_in[1];
    const float* conv1_b  = (const float*)d_in[2];
    const float* bn1_g    = (const float*)d_in[3];
    const float* bn1_b    = (const float*)d_in[4];
    const float* bn1_rm   = (const float*)d_in[5];
    const float* bn1_rv   = (const float*)d_in[6];
    const float* comp_w   = (const float*)d_in[7];
    const float* comp_b   = (const float*)d_in[8];
    const float* proj_w   = (const float*)d_in[9];
    const float* proj_b   = (const float*)d_in[10];
    const float* gates_w  = (const float*)d_in[11];
    const float* gates_b  = (const float*)d_in[12];
    const float* retention= (const float*)d_in[13];
    const float* expln_g  = (const float*)d_in[14];
    const float* expln_b  = (const float*)d_in[15];
    const float* ln_g     = (const float*)d_in[16];
    const float* ln_b     = (const float*)d_in[17];
    const float* attn_in_w  = (const float*)d_in[18];
    const float* attn_in_b  = (const float*)d_in[19];
    const float* attn_out_w = (const float*)d_in[20];
    const float* attn_out_b = (const float*)d_in[21];
    const float* bneck_w  = (const float*)d_in[22];
    const float* bneck_b  = (const float*)d_in[23];
    const float* bn2_g    = (const float*)d_in[24];
    const float* bn2_b    = (const float*)d_in[25];
    const float* bn2_rm   = (const float*)d_in[26];
    const float* bn2_rv   = (const float*)d_in[27];
    const float* out_w    = (const float*)d_in[28];
    const float* out_b    = (const float*)d_in[29];
    float* out = (float*)d_out;

    // ---- workspace layout (~240 MiB) ----
    char* base = (char*)d_ws;
    size_t off = 0;
    auto alloc = [&](size_t nbytes) -> char* {
        char* p = base + off;
        off += (nbytes + 255) & ~(size_t)255;
        return p;
    };
    __hip_bfloat16* seq_bf = (__hip_bfloat16*)alloc((size_t)B_ * TT * H_ * 2);   // 126 MB
    // union (42 MB): scan f32 o/tanh x2 layers (32 MB) / attn U+sbar+wkd+wvd
    size_t g_bytes = (size_t)B_ * NGATE_ * 2;                                    // 21 MB
    char* un = alloc(2 * g_bytes);
    float* opreA = (float*)un;                                    // 8 MB (layer1)
    float* tcnA  = (float*)(un + (size_t)8 * 1024 * 1024);
    float* opreB = (float*)(un + (size_t)16 * 1024 * 1024);       // layer0
    float* tcnB  = (float*)(un + (size_t)24 * 1024 * 1024);
    __hip_bfloat16* U_bf    = (__hip_bfloat16*)un;                               // attn phase
    __hip_bfloat16* sbar_bf = (__hip_bfloat16*)(un + (size_t)16 * 1024 * 1024);
    __hip_bfloat16* wkd_bf  = (__hip_bfloat16*)(un + (size_t)32 * 1024 * 1024);
    __hip_bfloat16* wvd_bf  = (__hip_bfloat16*)(un + (size_t)35 * 1024 * 1024);
    __hip_bfloat16* feat_bf = (__hip_bfloat16*)alloc((size_t)B_ * TT * FEATK * 2); // 15.7 MB
    float*          c0t   = (float*)alloc((size_t)B_ * H_ * 4);   // transposed [j][B]
    float*          c1t   = (float*)alloc((size_t)B_ * H_ * 4);
    __hip_bfloat16* h0_bf = (__hip_bfloat16*)alloc((size_t)B_ * H_ * 2);
    __hip_bfloat16* q_bf  = (__hip_bfloat16*)alloc((size_t)B_ * H_ * 2);  // also fin
    __hip_bfloat16* fin_bf = q_bf;
    __hip_bfloat16* av_bf = (__hip_bfloat16*)alloc((size_t)B_ * H_ * 2);
    float*          lat_f = (float*)alloc((size_t)B_ * LAT_ * 4);
    __hip_bfloat16* w1p_bf = (__hip_bfloat16*)alloc((size_t)NGATE_ * 2 * H_ * 2); // 5.24 MB
    __hip_bfloat16* w0p_bf = (__hip_bfloat16*)alloc((size_t)NGATE_ * K0M * 2);    // 2.95 MB
    float*          bc_f  = (float*)alloc((size_t)NGATE_ * 4);
    __hip_bfloat16* ai_bf = (__hip_bfloat16*)alloc((size_t)H_ * H_ * 2);
    __hip_bfloat16* ao_bf = (__hip_bfloat16*)alloc((size_t)H_ * H_ * 2);
    __hip_bfloat16* bw_bf = (__hip_bfloat16*)alloc((size_t)LAT_ * H_ * 2);
    (void)ws_size; (void)in_sizes; (void)n_in; (void)out_size;

    // ---- weight conversion / composition / permutation + state zeroing ----
    const int WL = 5 * H_ * 2 * H_;
    perm_w1<<<(NGATE_ * 2 * H_) / 256, 256, 0, stream>>>(gates_w + WL, w1p_bf);
    build_w0m<<<NGATE_ / 4, 256, 0, stream>>>(gates_w, proj_w, proj_b, gates_b,
                                              w0p_bf, bc_f);
    cvt_bf16<<<256, 256, 0, stream>>>(attn_in_w, ai_bf, (long)H_ * H_);
    cvt_bf16<<<256, 256, 0, stream>>>(attn_out_w, ao_bf, (long)H_ * H_);
    cvt_bf16<<<64, 256, 0, stream>>>(bneck_w, bw_bf, (long)LAT_ * H_);
    zero_f32<<<2048, 256, 0, stream>>>(c0t, (long)2 * B_ * H_);   // c0t+c1t contiguous

    // ---- front-end: feat only (proj composed into layer0 weights) ----
    frontend_kernel<<<B_, 256, 0, stream>>>(x, conv1_w, conv1_b, bn1_g, bn1_b, bn1_rm,
                                            bn1_rv, comp_w, comp_b, feat_bf);

    // ---- recurrent scan (layer1(t) || layer0(t+1) dual pipeline) ----
    // layer0 @ t=0: K=64 (composed feat cols only; h=0)
    fused_gate_single<<<1024, 256, 0, stream>>>(
        feat_bf, TT * FEATK, (const __hip_bfloat16*)nullptr, 0, FEATK, FEATK,
        w0p_bf, K0M, bc_f, retention, c0t, opreB, tcnB);
    gate_ln<<<B_, 256, 0, stream>>>(opreB, tcnB, expln_g, expln_b,
                                    ln_g, ln_b, h0_bf, H_);

    for (int t = 0; t < TT - 1; ++t) {
        fused_gate_dual<<<2048, 256, 0, stream>>>(
            // z0 = layer1(t): K = t? 1024 : 512 (h1(-1)=0), ksplit 512
            h0_bf, H_, (t == 0) ? (const __hip_bfloat16*)nullptr
                                : seq_bf + (size_t)(t - 1) * H_,
            TT * H_, H_, (t == 0) ? H_ : 2 * H_,
            w1p_bf, 2 * H_, gates_b + NGATE_, retention + H_, c1t, opreA, tcnA,
            // z1 = layer0(t+1): K = 576 (64 composed feat + 512 h), ksplit 64
            feat_bf + (size_t)(t + 1) * FEATK, TT * FEATK, h0_bf, H_, FEATK, K0M,
            w0p_bf, K0M, bc_f, retention, c0t, opreB, tcnB);
        gate_ln_dual<<<2 * B_, 256, 0, stream>>>(
            opreA, tcnA, expln_g + H_, expln_b + H_, ln_g + H_, ln_b + H_,
            seq_bf + (size_t)t * H_, TT * H_,
            opreB, tcnB, expln_g, expln_b, ln_g, ln_b, h0_bf, H_);
    }
    // layer1 @ t=29
    fused_gate_single<<<1024, 256, 0, stream>>>(
        h0_bf, H_, seq_bf + (size_t)(TT - 2) * H_, TT * H_, H_, 2 * H_,
        w1p_bf, 2 * H_, gates_b + NGATE_, retention + H_, c1t, opreA, tcnA);
    gate_ln<<<B_, 256, 0, stream>>>(opreA, tcnA, expln_g + H_, expln_b + H_,
                                    ln_g + H_, ln_b + H_,
                                    seq_bf + (size_t)(TT - 1) * H_, TT * H_);

    // ---- attention (unchanged) ----
    build_wkd<<<4096, 256, 0, stream>>>(attn_in_w, wkd_bf);
    build_wvd<<<4096, 256, 0, stream>>>(attn_in_w, wvd_bf);

    gemm_bias<1><<<dim3(H_ / 128, B_ / 128), 256, 0, stream>>>(
        seq_bf + (size_t)29 * H_, TT * H_, (const __hip_bfloat16*)nullptr, 0, H_,
        ai_bf, H_, attn_in_b, (void*)q_bf, H_, H_);

    gemm_bias<1><<<dim3(2048 / 128, B_ / 128), 256, 0, stream>>>(
        q_bf, H_, (const __hip_bfloat16*)nullptr, 0, H_,
        wkd_bf, H_, (const float*)nullptr, (void*)U_bf, 2048, H_);

    attn_fused<<<B_, 256, 0, stream>>>(seq_bf, U_bf, sbar_bf);

    gemm_bias<1><<<dim3(H_ / 128, B_ / 128), 256, 0, stream>>>(
        sbar_bf, 2048, (const __hip_bfloat16*)nullptr, 0, 2048,
        wvd_bf, 2048, attn_in_b + 2 * H_, (void*)av_bf, H_, 2048);

    gemm_bias<1><<<dim3(H_ / 128, B_ / 128), 256, 0, stream>>>(
        av_bf, H_, (const __hip_bfloat16*)nullptr, 0, H_,
        ao_bf, H_, attn_out_b, (void*)fin_bf, H_, H_);

    gemm_bias<0><<<dim3(LAT_ / 128, B_ / 128), 256, 0, stream>>>(
        fin_bf, H_, (const __hip_bfloat16*)nullptr, 0, H_,
        bw_bf, H_, bneck_b, (void*)lat_f, LAT_, H_);
    head_kernel<<<B_, 128, 0, stream>>>(lat_f, bn2_g, bn2_b, bn2_rm, bn2_rv,
                                        out_w, out_b, out);
}

// Round 11
// 2765.420 us; speedup vs baseline: 1.0079x; 1.0079x over previous
//
#include <hip/hip_runtime.h>
#include <hip/hip_bf16.h>

// Problem constants
#define B_   4096
#define T_   60
#define TT   30          // pooled sequence length
#define H_   512
#define L_   2
#define NH_  4
#define DH_  128
#define LAT_ 128
#define OUT_ 14
#define NGATE_ (5*H_)    // 2560
#define EPSF 1e-5f
#define FEATK 64         // feat padded to 64 (GEMM K granularity)
#define K0M  (FEATK + H_)   // 576: layer0 merged K (composed feat + h)

typedef __attribute__((ext_vector_type(8))) short bf16x8;
typedef __attribute__((ext_vector_type(4))) short bf16x4;
typedef __attribute__((ext_vector_type(4))) float f32x4;

__device__ __forceinline__ float sigmoidf_(float x) { return 1.0f / (1.0f + __expf(-x)); }
__device__ __forceinline__ float bf2f(short s) {
    return __uint_as_float(((unsigned)(unsigned short)s) << 16);
}

__device__ __forceinline__ void async_load16(const void* g, void* l) {
    __builtin_amdgcn_global_load_lds((const __attribute__((address_space(1))) void*)g,
                                     (__attribute__((address_space(3))) void*)l, 16, 0, 0);
}

// Gate-row permutation: original n = g*512 + j  ->  n' = (j>>4)*80 + g*16 + (j&15).
__device__ __forceinline__ int perm_row(int n) {
    int g = n >> 9, j = n & 511;
    return (j >> 4) * 80 + g * 16 + (j & 15);
}

// ---------------------------------------------------------------------------
// Utility kernels
// ---------------------------------------------------------------------------
__global__ __launch_bounds__(256) void cvt_bf16(const float* __restrict__ in,
                                                __hip_bfloat16* __restrict__ out, long n) {
    long i = (long)blockIdx.x * blockDim.x + threadIdx.x;
    long stride = (long)gridDim.x * blockDim.x;
    for (; i < n; i += stride) out[i] = __float2bfloat16(in[i]);
}

__global__ __launch_bounds__(256) void zero_f32(float* __restrict__ p, long n) {
    long i = (long)blockIdx.x * blockDim.x + threadIdx.x;
    long stride = (long)gridDim.x * blockDim.x;
    for (; i < n; i += stride) p[i] = 0.0f;
}

// layer1 gate weights f32 -> bf16, rows permuted for the fused kernel
__global__ __launch_bounds__(256)
void perm_w1(const float* __restrict__ gw, __hip_bfloat16* __restrict__ w1p) {
    long i = (long)blockIdx.x * 256 + threadIdx.x;       // 2560*1024
    if (i >= (long)NGATE_ * 2 * H_) return;
    int n = (int)(i >> 10), k = (int)(i & 1023);
    w1p[(long)perm_row(n) * (2 * H_) + k] = __float2bfloat16(gw[i]);
}

// Compose proj into layer0's input weights; rows permuted.
__global__ __launch_bounds__(256)
void build_w0m(const float* __restrict__ gw, const float* __restrict__ pw,
               const float* __restrict__ pb, const float* __restrict__ gb,
               __hip_bfloat16* __restrict__ w0p, float* __restrict__ bc) {
    const int tid = threadIdx.x;
    const int n = blockIdx.x * 4 + (tid >> 6);   // 640 blocks * 4 = 2560 rows
    const int f = tid & 63;
    const long np = perm_row(n);
    const float* wrow = gw + (long)n * (2 * H_);  // layer0 gate row [1024]
    float acc = 0.f;
    if (f < 44) {
        for (int k = 0; k < H_; ++k) acc += wrow[k] * pw[k * 44 + f];
    }
    w0p[np * K0M + f] = __float2bfloat16(acc);
    #pragma unroll
    for (int j = 0; j < 8; ++j) {
        int col = f * 8 + j;
        w0p[np * K0M + FEATK + col] = __float2bfloat16(wrow[H_ + col]);
    }
    float s = 0.f;
    #pragma unroll
    for (int j = 0; j < 8; ++j) s += wrow[f * 8 + j] * pb[f * 8 + j];
    #pragma unroll
    for (int off = 32; off > 0; off >>= 1) s += __shfl_down(s, off, 64);
    if (f == 0) bc[n] = gb[n] + s;
}

// Block-diagonal W_k^T for attention (unchanged)
__global__ __launch_bounds__(256)
void build_wkd(const float* __restrict__ aiw, __hip_bfloat16* __restrict__ wkd) {
    int i = blockIdx.x * 256 + threadIdx.x;          // 2048*512
    if (i >= 2048 * 512) return;
    int n = i >> 9, k = i & 511;
    float v = ((k >> 7) == (n >> 9)) ? aiw[(H_ + k) * H_ + (n & 511)] : 0.f;
    wkd[i] = __float2bfloat16(v);
}

__global__ __launch_bounds__(256)
void build_wvd(const float* __restrict__ aiw, __hip_bfloat16* __restrict__ wvd) {
    int i = blockIdx.x * 256 + threadIdx.x;          // 512*2048
    if (i >= 512 * 2048) return;
    int n = i >> 11, k = i & 2047;
    float v = ((k >> 9) == (n >> 7)) ? aiw[(2 * H_ + n) * H_ + (k & 511)] : 0.f;
    wvd[i] = __float2bfloat16(v);
}

// ---------------------------------------------------------------------------
// Front-end (unchanged)
// ---------------------------------------------------------------------------
__global__ __launch_bounds__(256)
void frontend_kernel(const float* __restrict__ x,
                     const float* __restrict__ cw, const float* __restrict__ cb,
                     const float* __restrict__ bg, const float* __restrict__ bb,
                     const float* __restrict__ brm, const float* __restrict__ brv,
                     const float* __restrict__ compw, const float* __restrict__ compb,
                     __hip_bfloat16* __restrict__ feat_out) {
    const int b = blockIdx.x, tid = threadIdx.x;
    __shared__ float xs[T_ * 17];
    __shared__ float ybuf[24][T_];
    __shared__ float feat[TT][44];

    for (int i = tid; i < T_ * 17; i += 256) xs[i] = x[(long)b * T_ * 17 + i];
    __syncthreads();

    for (int i = tid; i < 24 * T_; i += 256) {
        int oc = i / T_, t = i % T_;
        float acc = cb[oc];
        #pragma unroll
        for (int kk = 0; kk < 3; ++kk) {
            int tt = t + kk - 1;
            if (tt >= 0 && tt < T_) {
                #pragma unroll
                for (int ic = 0; ic < 9; ++ic)
                    acc += xs[tt * 17 + ic] * cw[(oc * 9 + ic) * 3 + kk];
            }
        }
        acc = fmaxf(acc, 0.f);
        acc = (acc - brm[oc]) * rsqrtf(brv[oc] + EPSF) * bg[oc] + bb[oc];
        ybuf[oc][t] = acc;
    }
    __syncthreads();

    for (int i = tid; i < TT * 24; i += 256) {
        int u = i / 24, oc = i % 24;
        feat[u][oc] = fmaxf(ybuf[oc][2 * u], ybuf[oc][2 * u + 1]);
    }
    for (int i = tid; i < TT * 20; i += 256) {
        int u = i / 20, oc = i % 20;
        float acc = compb[oc];
        #pragma unroll
        for (int j = 0; j < 8; ++j) acc += xs[u * 17 + 9 + j] * compw[oc * 8 + j];
        feat[u][24 + oc] = fmaxf(acc, 0.f);
    }
    __syncthreads();

    for (int i = tid; i < TT * FEATK; i += 256) {
        int u = i >> 6, c = i & 63;
        float v = (c < 44) ? feat[u][c] : 0.f;
        feat_out[((long)b * TT + u) * FEATK + c] = __float2bfloat16(v);
    }
}

// ---------------------------------------------------------------------------
// bf16 MFMA GEMM core (BK=64, proven) — kept for the attention chain.
// ---------------------------------------------------------------------------
template <int WRITE_BF16>
__device__ __forceinline__
void gemm_core(const __hip_bfloat16* __restrict__ A0, int lda0,
               const __hip_bfloat16* __restrict__ A1, int lda1, int ksplit,
               const __hip_bfloat16* __restrict__ W, int ldw,
               const float* __restrict__ bias,
               void* __restrict__ Cout, int ldc, int K, int bx, int by) {
    __shared__ __hip_bfloat16 As[128 * 64];
    __shared__ __hip_bfloat16 Bs[128 * 64];
    const int tid = threadIdx.x;
    const int wave = tid >> 6, lane = tid & 63;
    const long m0 = (long)by * 128;
    const long n0 = (long)bx * 128;

    f32x4 acc[4][4] = {};

    for (int k0 = 0; k0 < K; k0 += 64) {
        __syncthreads();
        #pragma unroll
        for (int it = 0; it < 4; ++it) {
            int id = it * 256 + tid;
            int row = id >> 3;
            int kc = ((id & 7) ^ (row & 7)) << 3;
            int gk = k0 + kc;
            const __hip_bfloat16* srcA;
            if (gk < ksplit) srcA = A0 + (m0 + row) * (long)lda0 + gk;
            else             srcA = A1 + (m0 + row) * (long)lda1 + (gk - ksplit);
            async_load16(srcA, &As[id * 8]);
            const __hip_bfloat16* srcB = W + (n0 + row) * (long)ldw + gk;
            async_load16(srcB, &Bs[id * 8]);
        }
        __syncthreads();
        #pragma unroll
        for (int ks = 0; ks < 2; ++ks) {
            const int kb = ((ks * 4 + (lane >> 4)) ^ (lane & 7)) << 3;
            const int ar = (wave >> 1) * 64 + (lane & 15);
            const int br = (wave & 1) * 64 + (lane & 15);
            bf16x8 afr[4], bfr[4];
            #pragma unroll
            for (int i = 0; i < 4; ++i) afr[i] = *(const bf16x8*)&As[(ar + i * 16) * 64 + kb];
            #pragma unroll
            for (int i = 0; i < 4; ++i) bfr[i] = *(const bf16x8*)&Bs[(br + i * 16) * 64 + kb];
            #pragma unroll
            for (int mi = 0; mi < 4; ++mi)
                #pragma unroll
                for (int ni = 0; ni < 4; ++ni)
                    acc[mi][ni] = __builtin_amdgcn_mfma_f32_16x16x32_bf16(afr[mi], bfr[ni], acc[mi][ni], 0, 0, 0);
        }
    }

    const int cr = (lane >> 4) * 4;
    const int ccol = lane & 15;
    #pragma unroll
    for (int ni = 0; ni < 4; ++ni) {
        long col = n0 + (wave & 1) * 64 + ni * 16 + ccol;
        float bv = bias ? bias[col] : 0.f;
        #pragma unroll
        for (int mi = 0; mi < 4; ++mi) {
            long rowb = m0 + (wave >> 1) * 64 + mi * 16 + cr;
            #pragma unroll
            for (int r = 0; r < 4; ++r) {
                float v = acc[mi][ni][r] + bv;
                if (WRITE_BF16)
                    ((__hip_bfloat16*)Cout)[(rowb + r) * (long)ldc + col] = __float2bfloat16(v);
                else
                    ((float*)Cout)[(rowb + r) * (long)ldc + col] = v;
            }
        }
    }
}

template <int WRITE_BF16>
__global__ __launch_bounds__(256)
void gemm_bias(const __hip_bfloat16* __restrict__ A0, int lda0,
               const __hip_bfloat16* __restrict__ A1, int lda1, int ksplit,
               const __hip_bfloat16* __restrict__ W, int ldw,
               const float* __restrict__ bias,
               void* __restrict__ Cout, int ldc, int K) {
    gemm_core<WRITE_BF16>(A0, lda0, A1, lda1, ksplit, W, ldw, bias, Cout, ldc, K,
                          blockIdx.x, blockIdx.y);
}

// ---------------------------------------------------------------------------
// R21 fused gate GEMM: R20 hybrid (W in 20 KB dbuf LDS, A direct-to-register)
// + REGISTER double-buffer for A. R20's failure mode: A loads were issued
// after the slab barrier and consumed immediately -> serial ~200-400cy
// latency per slab that cancelled the occupancy gain (occ 29->44% but dur
// unchanged at 78 us). Fix: issue slab kk+1's A loads into aNxt right after
// the barrier (alongside the W stage), compute slab kk from aCur (already
// resident), then aCur <- aNxt. The copy's implicit vmcnt wait lands AFTER
// the MFMA block, so A latency hides under compute — restoring the prefetch
// depth the old LDS path had, without its 32 KB LDS cost.
// Epilogue/f32 handoff identical to R14..R20 (absmax 0.0042 proven).
// ---------------------------------------------------------------------------
__device__ __forceinline__
void fused_gate_core(const __hip_bfloat16* __restrict__ A0, int lda0,
                     const __hip_bfloat16* __restrict__ A1, int lda1,
                     int ksplit, int K,
                     const __hip_bfloat16* __restrict__ Wp, int ldw,
                     const float* __restrict__ bias,
                     const float* __restrict__ ret,
                     float* __restrict__ c_t,
                     float* __restrict__ opre,
                     float* __restrict__ tcn,
                     int m, int nblk) {
    __shared__ __hip_bfloat16 Bs[2][80 * 64];
    const int tid = threadIdx.x;
    const int wave = tid >> 6, lane = tid & 63;
    const long m0 = (long)m * 128;
    const int n0row = nblk * 80;
    const int jbase = nblk * 16;
    const int rsel = lane & 15;
    const int q = lane >> 4;

    // W staging addresses (hoisted, it-invariant swizzle) — identical to R19/R20.
    const int kc = ((tid & 7) ^ ((tid >> 3) & 7)) << 3;
    const int srow = tid >> 3;                       // 0..31
    const __hip_bfloat16* pB_t = Wp + (long)(n0row + srow) * ldw + kc;

    // Direct per-lane A fragment pointers (R17-proven layout).
    const long arow = m0 + wave * 32 + rsel;
    const __hip_bfloat16* pa0 = A0 + arow * (long)lda0 + q * 8;
    const __hip_bfloat16* pa1 =
        A1 ? (A1 + arow * (long)lda1 + q * 8 - ksplit) : pa0;
    const long a0s16 = (long)16 * lda0;              // mi stride (rows)
    const long a1s16 = (long)16 * lda1;

    const int ks_slab = ksplit >> 6;
    const int nslab = K >> 6;

    auto stage = [&](int hb, int kk) {
        const long koff = (long)kk << 6;
        #pragma unroll
        for (int it = 0; it < 2; ++it)
            async_load16(pB_t + (long)it * 32 * ldw + koff,
                         &Bs[hb][it * 2048 + tid * 8]);
        if (tid < 128)
            async_load16(pB_t + (long)64 * ldw + koff,
                         &Bs[hb][4096 + tid * 8]);
    };
    auto loadA = [&](int kk, bf16x8 (&dst)[2][2]) {
        const __hip_bfloat16* pa;
        long as16;
        if (kk < ks_slab) { pa = pa0 + ((long)kk << 6); as16 = a0s16; }
        else              { pa = pa1 + ((long)kk << 6); as16 = a1s16; }
        #pragma unroll
        for (int mi = 0; mi < 2; ++mi)
            #pragma unroll
            for (int ks = 0; ks < 2; ++ks)
                dst[mi][ks] = *(const bf16x8*)(pa + mi * as16 + ks * 32);
    };

    stage(0, 0);
    bf16x8 aCur[2][2], aNxt[2][2];
    loadA(0, aCur);
    f32x4 acc[2][5] = {};

    for (int kk = 0; kk < nslab; ++kk) {
        const int hb = kk & 1;
        const bool more = (kk + 1 < nslab);
        __syncthreads();
        if (more) {
            stage(hb ^ 1, kk + 1);
            loadA(kk + 1, aNxt);     // overlaps with this slab's MFMAs
        }
        #pragma unroll
        for (int ks = 0; ks < 2; ++ks) {
            const int kb = ((ks * 4 + q) ^ (lane & 7)) << 3;
            bf16x8 bfr[5];
            #pragma unroll
            for (int i = 0; i < 5; ++i)
                bfr[i] = *(const bf16x8*)&Bs[hb][(i * 16 + rsel) * 64 + kb];
            #pragma unroll
            for (int mi = 0; mi < 2; ++mi)
                #pragma unroll
                for (int ni = 0; ni < 5; ++ni)
                    acc[mi][ni] = __builtin_amdgcn_mfma_f32_16x16x32_bf16(bfr[ni], aCur[mi][ks], acc[mi][ni], 0, 0, 0);
        }
        if (more) {
            #pragma unroll
            for (int mi = 0; mi < 2; ++mi)
                #pragma unroll
                for (int ks = 0; ks < 2; ++ks)
                    aCur[mi][ks] = aNxt[mi][ks];
        }
    }

    // Fused epilogue: per thread 2 b-rows x 4 j, full gate quintuple in-register.
    #pragma unroll
    for (int mi = 0; mi < 2; ++mi) {
        const long b = m0 + wave * 32 + mi * 16 + rsel;
        f32x4 ov, tv;
        #pragma unroll
        for (int r = 0; r < 4; ++r) {
            const int jg = jbase + 4 * q + r;
            float f  = sigmoidf_(acc[mi][0][r] + bias[jg]);
            float ii = sigmoidf_(acc[mi][1][r] + bias[512 + jg]);
            float o  = sigmoidf_(acc[mi][2][r] + bias[1024 + jg]);
            float cc = tanhf(acc[mi][3][r] + bias[1536 + jg]);
            float mg = sigmoidf_(acc[mi][4][r] + bias[2048 + jg]);
            float cold = c_t[(long)jg * B_ + b];
            float rr = ret[jg];
            float cn = f * cold + ii * cc;
            cn = cn * rr + (1.f - rr) * cold;
            cn = mg * cn + (1.f - mg) * cold;
            c_t[(long)jg * B_ + b] = cn;
            ov[r] = o;
            tv[r] = tanhf(cn);
        }
        *(f32x4*)&opre[b * H_ + jbase + 4 * q] = ov;
        *(f32x4*)&tcn [b * H_ + jbase + 4 * q] = tv;
    }
}

// Single-layer wrapper (boundary steps). grid = 1024 (32 m x 32 n), XCD-grouped.
__global__ __launch_bounds__(256, 4)
void fused_gate_single(const __hip_bfloat16* A0, int lda0, const __hip_bfloat16* A1,
                       int lda1, int ksplit, int K,
                       const __hip_bfloat16* Wp, int ldw,
                       const float* bias, const float* ret, float* c_t,
                       float* opre, float* tcn) {
    const int id = blockIdx.x;
    const int xcd = id & 7;
    const int rest = id >> 3;                 // [0,128)
    const int m = xcd * 4 + (rest & 3);
    const int n = (rest >> 2) & 31;
    fused_gate_core(A0, lda0, A1, lda1, ksplit, K, Wp, ldw, bias, ret, c_t,
                    opre, tcn, m, n);
}

// Dual-layer wrapper. grid = 2048: xcd=id&7; rest bits [0:1]=m-sub, [2:6]=n, [7]=z.
__global__ __launch_bounds__(256, 4)
void fused_gate_dual(const __hip_bfloat16* A0a, int lda0a, const __hip_bfloat16* A1a,
                     int lda1a, int ksplita, int Ka,
                     const __hip_bfloat16* Wpa, int ldwa,
                     const float* biasa, const float* reta, float* cta,
                     float* oprea, float* tcna,
                     const __hip_bfloat16* A0b, int lda0b, const __hip_bfloat16* A1b,
                     int lda1b, int ksplitb, int Kb,
                     const __hip_bfloat16* Wpb, int ldwb,
                     const float* biasb, const float* retb, float* ctb,
                     float* opreb, float* tcnb) {
    const int id = blockIdx.x;
    const int xcd = id & 7;
    const int rest = id >> 3;                 // [0,256)
    const int m = xcd * 4 + (rest & 3);
    const int n = (rest >> 2) & 31;
    const int z = rest >> 7;
    if (z == 0)
        fused_gate_core(A0a, lda0a, A1a, lda1a, ksplita, Ka, Wpa, ldwa,
                        biasa, reta, cta, oprea, tcna, m, n);
    else
        fused_gate_core(A0b, lda0b, A1b, lda1b, ksplitb, Kb, Wpb, ldwb,
                        biasb, retb, ctb, opreb, tcnb, m, n);
}

// ---------------------------------------------------------------------------
// gate_ln: the two LayerNorms (need full-j stats) on f32 o/tanh(c).
// ---------------------------------------------------------------------------
__device__ __forceinline__ void block_reduce2(float& a, float& b, float* red) {
    #pragma unroll
    for (int off = 32; off > 0; off >>= 1) {
        a += __shfl_down(a, off, 64);
        b += __shfl_down(b, off, 64);
    }
    int lane = threadIdx.x & 63, w = threadIdx.x >> 6;
    if (lane == 0) { red[w] = a; red[8 + w] = b; }
    __syncthreads();
    a = red[0] + red[1] + red[2] + red[3];
    b = red[8] + red[9] + red[10] + red[11];
    __syncthreads();
}

__device__ __forceinline__
void gate_ln_body(const float* __restrict__ opre,
                  const float* __restrict__ tcn,
                  const float* __restrict__ elg, const float* __restrict__ elb,
                  const float* __restrict__ lng, const float* __restrict__ lnb,
                  __hip_bfloat16* __restrict__ hout, long hstride, int b) {
    const int tid = threadIdx.x;
    __shared__ float red[16];

    float o_[2], t_[2];
    float s = 0.f, s2 = 0.f;
    #pragma unroll
    for (int u = 0; u < 2; ++u) {
        int j = tid + u * 256;
        float o = opre[(long)b * H_ + j];
        float t = tcn[(long)b * H_ + j];
        o_[u] = o; t_[u] = t;
        s += o; s2 += o * o;
    }
    block_reduce2(s, s2, red);
    float mean = s * (1.f / H_);
    float var = s2 * (1.f / H_) - mean * mean;
    float rstd = rsqrtf(var + EPSF);

    float val[2];
    float s3 = 0.f, s4 = 0.f;
    #pragma unroll
    for (int u = 0; u < 2; ++u) {
        int j = tid + u * 256;
        float on = (o_[u] - mean) * rstd * elg[j] + elb[j];
        float v = sigmoidf_(on) * t_[u];
        val[u] = v; s3 += v; s4 += v * v;
    }
    block_reduce2(s3, s4, red);
    float mean2 = s3 * (1.f / H_);
    float var2 = s4 * (1.f / H_) - mean2 * mean2;
    float rstd2 = rsqrtf(var2 + EPSF);
    #pragma unroll
    for (int u = 0; u < 2; ++u) {
        int j = tid + u * 256;
        float h = (val[u] - mean2) * rstd2 * lng[j] + lnb[j];
        hout[(long)b * hstride + j] = __float2bfloat16(h);
    }
}

__global__ __launch_bounds__(256)
void gate_ln(const float* __restrict__ opre,
             const float* __restrict__ tcn,
             const float* __restrict__ elg, const float* __restrict__ elb,
             const float* __restrict__ lng, const float* __restrict__ lnb,
             __hip_bfloat16* __restrict__ hout, long hstride) {
    gate_ln_body(opre, tcn, elg, elb, lng, lnb, hout, hstride, blockIdx.x);
}

__global__ __launch_bounds__(256)
void gate_ln_dual(const float* oa, const float* ta,
                  const float* elga, const float* elba,
                  const float* lnga, const float* lnba,
                  __hip_bfloat16* houta, long hstridea,
                  const float* ob, const float* tb,
                  const float* elgb, const float* elbb,
                  const float* lngb, const float* lnbb,
                  __hip_bfloat16* houtb, long hstrideb) {
    int bid = blockIdx.x;
    bool isB = bid >= B_;
    int b = isB ? bid - B_ : bid;
    gate_ln_body(isB ? ob : oa, isB ? tb : ta,
                 isB ? elgb : elga, isB ? elbb : elba,
                 isB ? lngb : lnga, isB ? lnbb : lnba,
                 isB ? houtb : houta, isB ? hstrideb : hstridea, b);
}

// ---------------------------------------------------------------------------
// R11 fused attention (unchanged).
// ---------------------------------------------------------------------------
__global__ __launch_bounds__(256)
void attn_fused(const __hip_bfloat16* __restrict__ seq,
                const __hip_bfloat16* __restrict__ U,
                __hip_bfloat16* __restrict__ sbar) {
    const int b = blockIdx.x, tid = threadIdx.x;
    const int h = tid >> 6, lane = tid & 63;
    const int c0 = lane * 8;
    __shared__ float ps[NH_ * TT];      // 480 B
    const float scale = 0.08838834764831845f;   // 1/sqrt(128)

    float uq[8];
    {
        bf16x8 uv = *(const bf16x8*)&U[(size_t)b * (NH_ * H_) + h * H_ + c0];
        for (int j = 0; j < 8; ++j) uq[j] = bf2f(uv[j]);
    }
    const __hip_bfloat16* srow = seq + (size_t)b * TT * H_;

    for (int t = 0; t < TT; ++t) {
        bf16x8 sv = *(const bf16x8*)&srow[t * H_ + c0];
        float a = 0.f;
        for (int j = 0; j < 8; ++j) a += uq[j] * bf2f(sv[j]);
        a += __shfl_xor(a, 32);
        a += __shfl_xor(a, 16);
        a += __shfl_xor(a, 8);
        a += __shfl_xor(a, 4);
        a += __shfl_xor(a, 2);
        a += __shfl_xor(a, 1);
        if (lane == 0) ps[h * TT + t] = a * scale;
    }
    __syncthreads();

    float mx = -1e30f;
    for (int t = 0; t < TT; ++t) mx = fmaxf(mx, ps[h * TT + t]);
    float den = 0.f;
    for (int t = 0; t < TT; ++t) den += __expf(ps[h * TT + t] - mx);
    float inv = 1.f / den;

    float accv[8];
    for (int j = 0; j < 8; ++j) accv[j] = 0.f;
    for (int t = 0; t < TT; ++t) {
        float w = __expf(ps[h * TT + t] - mx) * inv;
        bf16x8 sv = *(const bf16x8*)&srow[t * H_ + c0];
        for (int j = 0; j < 8; ++j) accv[j] += w * bf2f(sv[j]);
    }
    bf16x8 outv;
    for (int j = 0; j < 8; ++j) {
        __hip_bfloat16 hv = __float2bfloat16(accv[j]);
        outv[j] = *(short*)&hv;
    }
    *(bf16x8*)&sbar[(size_t)b * (NH_ * H_) + h * H_ + c0] = outv;
}

// ---------------------------------------------------------------------------
// Head (unchanged).
// ---------------------------------------------------------------------------
__global__ __launch_bounds__(128)
void head_kernel(const float* __restrict__ lat_in,
                 const float* __restrict__ g2, const float* __restrict__ b2,
                 const float* __restrict__ rm2, const float* __restrict__ rv2,
                 const float* __restrict__ ow, const float* __restrict__ ob,
                 float* __restrict__ out) {
    const int b = blockIdx.x, tid = threadIdx.x;
    __shared__ float ls[LAT_];
    float a = lat_in[(long)b * LAT_ + tid];
    ls[tid] = (a - rm2[tid]) * rsqrtf(rv2[tid] + EPSF) * g2[tid] + b2[tid];
    __syncthreads();
    if (tid < OUT_) {
        float acc = ob[tid];
        #pragma unroll 4
        for (int j = 0; j < LAT_; ++j) acc += ls[j] * ow[tid * LAT_ + j];
        out[(long)b * OUT_ + tid] = acc;
    }
}

// ---------------------------------------------------------------------------
extern "C" void kernel_launch(void* const* d_in, const int* in_sizes, int n_in,
                              void* d_out, int out_size, void* d_ws, size_t ws_size,
                              hipStream_t stream) {
    const float* x        = (const float*)d_in[0];
    const float* conv1_w  = (const float*)d_in[1];
    const float* conv1_b  = (const float*)d_in[2];
    const float* bn1_g    = (const float*)d_in[3];
    const float* bn1_b    = (const float*)d_in[4];
    const float* bn1_rm   = (const float*)d_in[5];
    const float* bn1_rv   = (const float*)d_in[6];
    const float* comp_w   = (const float*)d_in[7];
    const float* comp_b   = (const float*)d_in[8];
    const float* proj_w   = (const float*)d_in[9];
    const float* proj_b   = (const float*)d_in[10];
    const float* gates_w  = (const float*)d_in[11];
    const float* gates_b  = (const float*)d_in[12];
    const float* retention= (const float*)d_in[13];
    const float* expln_g  = (const float*)d_in[14];
    const float* expln_b  = (const float*)d_in[15];
    const float* ln_g     = (const float*)d_in[16];
    const float* ln_b     = (const float*)d_in[17];
    const float* attn_in_w  = (const float*)d_in[18];
    const float* attn_in_b  = (const float*)d_in[19];
    const float* attn_out_w = (const float*)d_in[20];
    const float* attn_out_b = (const float*)d_in[21];
    const float* bneck_w  = (const float*)d_in[22];
    const float* bneck_b  = (const float*)d_in[23];
    const float* bn2_g    = (const float*)d_in[24];
    const float* bn2_b    = (const float*)d_in[25];
    const float* bn2_rm   = (const float*)d_in[26];
    const float* bn2_rv   = (const float*)d_in[27];
    const float* out_w    = (const float*)d_in[28];
    const float* out_b    = (const float*)d_in[29];
    float* out = (float*)d_out;

    // ---- workspace layout (~240 MiB) ----
    char* base = (char*)d_ws;
    size_t off = 0;
    auto alloc = [&](size_t nbytes) -> char* {
        char* p = base + off;
        off += (nbytes + 255) & ~(size_t)255;
        return p;
    };
    __hip_bfloat16* seq_bf = (__hip_bfloat16*)alloc((size_t)B_ * TT * H_ * 2);   // 126 MB
    // union (42 MB): scan f32 o/tanh x2 layers (32 MB) / attn U+sbar+wkd+wvd
    size_t g_bytes = (size_t)B_ * NGATE_ * 2;                                    // 21 MB
    char* un = alloc(2 * g_bytes);
    float* opreA = (float*)un;                                    // 8 MB (layer1)
    float* tcnA  = (float*)(un + (size_t)8 * 1024 * 1024);
    float* opreB = (float*)(un + (size_t)16 * 1024 * 1024);       // layer0
    float* tcnB  = (float*)(un + (size_t)24 * 1024 * 1024);
    __hip_bfloat16* U_bf    = (__hip_bfloat16*)un;                               // attn phase
    __hip_bfloat16* sbar_bf = (__hip_bfloat16*)(un + (size_t)16 * 1024 * 1024);
    __hip_bfloat16* wkd_bf  = (__hip_bfloat16*)(un + (size_t)32 * 1024 * 1024);
    __hip_bfloat16* wvd_bf  = (__hip_bfloat16*)(un + (size_t)35 * 1024 * 1024);
    __hip_bfloat16* feat_bf = (__hip_bfloat16*)alloc((size_t)B_ * TT * FEATK * 2); // 15.7 MB
    float*          c0t   = (float*)alloc((size_t)B_ * H_ * 4);   // transposed [j][B]
    float*          c1t   = (float*)alloc((size_t)B_ * H_ * 4);
    __hip_bfloat16* h0_bf = (__hip_bfloat16*)alloc((size_t)B_ * H_ * 2);
    __hip_bfloat16* q_bf  = (__hip_bfloat16*)alloc((size_t)B_ * H_ * 2);  // also fin
    __hip_bfloat16* fin_bf = q_bf;
    __hip_bfloat16* av_bf = (__hip_bfloat16*)alloc((size_t)B_ * H_ * 2);
    float*          lat_f = (float*)alloc((size_t)B_ * LAT_ * 4);
    __hip_bfloat16* w1p_bf = (__hip_bfloat16*)alloc((size_t)NGATE_ * 2 * H_ * 2); // 5.24 MB
    __hip_bfloat16* w0p_bf = (__hip_bfloat16*)alloc((size_t)NGATE_ * K0M * 2);    // 2.95 MB
    float*          bc_f  = (float*)alloc((size_t)NGATE_ * 4);
    __hip_bfloat16* ai_bf = (__hip_bfloat16*)alloc((size_t)H_ * H_ * 2);
    __hip_bfloat16* ao_bf = (__hip_bfloat16*)alloc((size_t)H_ * H_ * 2);
    __hip_bfloat16* bw_bf = (__hip_bfloat16*)alloc((size_t)LAT_ * H_ * 2);
    (void)ws_size; (void)in_sizes; (void)n_in; (void)out_size;

    // ---- weight conversion / composition / permutation + state zeroing ----
    const int WL = 5 * H_ * 2 * H_;
    perm_w1<<<(NGATE_ * 2 * H_) / 256, 256, 0, stream>>>(gates_w + WL, w1p_bf);
    build_w0m<<<NGATE_ / 4, 256, 0, stream>>>(gates_w, proj_w, proj_b, gates_b,
                                              w0p_bf, bc_f);
    cvt_bf16<<<256, 256, 0, stream>>>(attn_in_w, ai_bf, (long)H_ * H_);
    cvt_bf16<<<256, 256, 0, stream>>>(attn_out_w, ao_bf, (long)H_ * H_);
    cvt_bf16<<<64, 256, 0, stream>>>(bneck_w, bw_bf, (long)LAT_ * H_);
    zero_f32<<<2048, 256, 0, stream>>>(c0t, (long)2 * B_ * H_);   // c0t+c1t contiguous

    // ---- front-end: feat only (proj composed into layer0 weights) ----
    frontend_kernel<<<B_, 256, 0, stream>>>(x, conv1_w, conv1_b, bn1_g, bn1_b, bn1_rm,
                                            bn1_rv, comp_w, comp_b, feat_bf);

    // ---- recurrent scan (layer1(t) || layer0(t+1) dual pipeline) ----
    // layer0 @ t=0: K=64 (composed feat cols only; h=0)
    fused_gate_single<<<1024, 256, 0, stream>>>(
        feat_bf, TT * FEATK, (const __hip_bfloat16*)nullptr, 0, FEATK, FEATK,
        w0p_bf, K0M, bc_f, retention, c0t, opreB, tcnB);
    gate_ln<<<B_, 256, 0, stream>>>(opreB, tcnB, expln_g, expln_b,
                                    ln_g, ln_b, h0_bf, H_);

    for (int t = 0; t < TT - 1; ++t) {
        fused_gate_dual<<<2048, 256, 0, stream>>>(
            // z0 = layer1(t): K = t? 1024 : 512 (h1(-1)=0), ksplit 512
            h0_bf, H_, (t == 0) ? (const __hip_bfloat16*)nullptr
                                : seq_bf + (size_t)(t - 1) * H_,
            TT * H_, H_, (t == 0) ? H_ : 2 * H_,
            w1p_bf, 2 * H_, gates_b + NGATE_, retention + H_, c1t, opreA, tcnA,
            // z1 = layer0(t+1): K = 576 (64 composed feat + 512 h), ksplit 64
            feat_bf + (size_t)(t + 1) * FEATK, TT * FEATK, h0_bf, H_, FEATK, K0M,
            w0p_bf, K0M, bc_f, retention, c0t, opreB, tcnB);
        gate_ln_dual<<<2 * B_, 256, 0, stream>>>(
            opreA, tcnA, expln_g + H_, expln_b + H_, ln_g + H_, ln_b + H_,
            seq_bf + (size_t)t * H_, TT * H_,
            opreB, tcnB, expln_g, expln_b, ln_g, ln_b, h0_bf, H_);
    }
    // layer1 @ t=29
    fused_gate_single<<<1024, 256, 0, stream>>>(
        h0_bf, H_, seq_bf + (size_t)(TT - 2) * H_, TT * H_, H_, 2 * H_,
        w1p_bf, 2 * H_, gates_b + NGATE_, retention + H_, c1t, opreA, tcnA);
    gate_ln<<<B_, 256, 0, stream>>>(opreA, tcnA, expln_g + H_, expln_b + H_,
                                    ln_g + H_, ln_b + H_,
                                    seq_bf + (size_t)(TT - 1) * H_, TT * H_);

    // ---- attention (unchanged) ----
    build_wkd<<<4096, 256, 0, stream>>>(attn_in_w, wkd_bf);
    build_wvd<<<4096, 256, 0, stream>>>(attn_in_w, wvd_bf);

    gemm_bias<1><<<dim3(H_ / 128, B_ / 128), 256, 0, stream>>>(
        seq_bf + (size_t)29 * H_, TT * H_, (const __hip_bfloat16*)nullptr, 0, H_,
        ai_bf, H_, attn_in_b, (void*)q_bf, H_, H_);

    gemm_bias<1><<<dim3(2048 / 128, B_ / 128), 256, 0, stream>>>(
        q_bf, H_, (const __hip_bfloat16*)nullptr, 0, H_,
        wkd_bf, H_, (const float*)nullptr, (void*)U_bf, 2048, H_);

    attn_fused<<<B_, 256, 0, stream>>>(seq_bf, U_bf, sbar_bf);

    gemm_bias<1><<<dim3(H_ / 128, B_ / 128), 256, 0, stream>>>(
        sbar_bf, 2048, (const __hip_bfloat16*)nullptr, 0, 2048,
        wvd_bf, 2048, attn_in_b + 2 * H_, (void*)av_bf, H_, 2048);

    gemm_bias<1><<<dim3(H_ / 128, B_ / 128), 256, 0, stream>>>(
        av_bf, H_, (const __hip_bfloat16*)nullptr, 0, H_,
        ao_bf, H_, attn_out_b, (void*)fin_bf, H_, H_);

    gemm_bias<0><<<dim3(LAT_ / 128, B_ / 128), 256, 0, stream>>>(
        fin_bf, H_, (const __hip_bfloat16*)nullptr, 0, H_,
        bw_bf, H_, bneck_b, (void*)lat_f, LAT_, H_);
    head_kernel<<<B_, 128, 0, stream>>>(lat_f, bn2_g, bn2_b, bn2_rm, bn2_rv,
                                        out_w, out_b, out);
}

// Round 12
// 2443.447 us; speedup vs baseline: 1.1407x; 1.1318x over previous
//
#include <hip/hip_runtime.h>
#include <hip/hip_bf16.h>
#include <hip/hip_fp16.h>

// Problem constants
#define B_   4096
#define T_   60
#define TT   30          // pooled sequence length
#define H_   512
#define L_   2
#define NH_  4
#define DH_  128
#define LAT_ 128
#define OUT_ 14
#define NGATE_ (5*H_)    // 2560
#define EPSF 1e-5f
#define FEATK 64         // feat padded to 64 (GEMM K granularity)
#define K0M  (FEATK + H_)   // 576: layer0 merged K (composed feat + h)

typedef __attribute__((ext_vector_type(8))) short bf16x8;
typedef __attribute__((ext_vector_type(4))) short sh4;     // 4 x 16-bit
typedef __attribute__((ext_vector_type(4))) float f32x4;

__device__ __forceinline__ float sigmoidf_(float x) { return 1.0f / (1.0f + __expf(-x)); }
__device__ __forceinline__ float bf2f(short s) {
    return __uint_as_float(((unsigned)(unsigned short)s) << 16);
}

__device__ __forceinline__ void async_load16(const void* g, void* l) {
    __builtin_amdgcn_global_load_lds((const __attribute__((address_space(1))) void*)g,
                                     (__attribute__((address_space(3))) void*)l, 16, 0, 0);
}

// Gate-row permutation: original n = g*512 + j  ->  n' = (j>>4)*80 + g*16 + (j&15).
__device__ __forceinline__ int perm_row(int n) {
    int g = n >> 9, j = n & 511;
    return (j >> 4) * 80 + g * 16 + (j & 15);
}

// ---------------------------------------------------------------------------
// Utility kernels
// ---------------------------------------------------------------------------
__global__ __launch_bounds__(256) void cvt_bf16(const float* __restrict__ in,
                                                __hip_bfloat16* __restrict__ out, long n) {
    long i = (long)blockIdx.x * blockDim.x + threadIdx.x;
    long stride = (long)gridDim.x * blockDim.x;
    for (; i < n; i += stride) out[i] = __float2bfloat16(in[i]);
}

__global__ __launch_bounds__(256) void zero_f32(float* __restrict__ p, long n) {
    long i = (long)blockIdx.x * blockDim.x + threadIdx.x;
    long stride = (long)gridDim.x * blockDim.x;
    for (; i < n; i += stride) p[i] = 0.0f;
}

// layer1 gate weights f32 -> bf16, rows permuted for the fused kernel
__global__ __launch_bounds__(256)
void perm_w1(const float* __restrict__ gw, __hip_bfloat16* __restrict__ w1p) {
    long i = (long)blockIdx.x * 256 + threadIdx.x;       // 2560*1024
    if (i >= (long)NGATE_ * 2 * H_) return;
    int n = (int)(i >> 10), k = (int)(i & 1023);
    w1p[(long)perm_row(n) * (2 * H_) + k] = __float2bfloat16(gw[i]);
}

// Compose proj into layer0's input weights; rows permuted.
__global__ __launch_bounds__(256)
void build_w0m(const float* __restrict__ gw, const float* __restrict__ pw,
               const float* __restrict__ pb, const float* __restrict__ gb,
               __hip_bfloat16* __restrict__ w0p, float* __restrict__ bc) {
    const int tid = threadIdx.x;
    const int n = blockIdx.x * 4 + (tid >> 6);   // 640 blocks * 4 = 2560 rows
    const int f = tid & 63;
    const long np = perm_row(n);
    const float* wrow = gw + (long)n * (2 * H_);  // layer0 gate row [1024]
    float acc = 0.f;
    if (f < 44) {
        for (int k = 0; k < H_; ++k) acc += wrow[k] * pw[k * 44 + f];
    }
    w0p[np * K0M + f] = __float2bfloat16(acc);
    #pragma unroll
    for (int j = 0; j < 8; ++j) {
        int col = f * 8 + j;
        w0p[np * K0M + FEATK + col] = __float2bfloat16(wrow[H_ + col]);
    }
    float s = 0.f;
    #pragma unroll
    for (int j = 0; j < 8; ++j) s += wrow[f * 8 + j] * pb[f * 8 + j];
    #pragma unroll
    for (int off = 32; off > 0; off >>= 1) s += __shfl_down(s, off, 64);
    if (f == 0) bc[n] = gb[n] + s;
}

// Block-diagonal W_k^T for attention (unchanged)
__global__ __launch_bounds__(256)
void build_wkd(const float* __restrict__ aiw, __hip_bfloat16* __restrict__ wkd) {
    int i = blockIdx.x * 256 + threadIdx.x;          // 2048*512
    if (i >= 2048 * 512) return;
    int n = i >> 9, k = i & 511;
    float v = ((k >> 7) == (n >> 9)) ? aiw[(H_ + k) * H_ + (n & 511)] : 0.f;
    wkd[i] = __float2bfloat16(v);
}

__global__ __launch_bounds__(256)
void build_wvd(const float* __restrict__ aiw, __hip_bfloat16* __restrict__ wvd) {
    int i = blockIdx.x * 256 + threadIdx.x;          // 512*2048
    if (i >= 512 * 2048) return;
    int n = i >> 11, k = i & 2047;
    float v = ((k >> 9) == (n >> 7)) ? aiw[(2 * H_ + n) * H_ + (k & 511)] : 0.f;
    wvd[i] = __float2bfloat16(v);
}

// ---------------------------------------------------------------------------
// Front-end (unchanged)
// ---------------------------------------------------------------------------
__global__ __launch_bounds__(256)
void frontend_kernel(const float* __restrict__ x,
                     const float* __restrict__ cw, const float* __restrict__ cb,
                     const float* __restrict__ bg, const float* __restrict__ bb,
                     const float* __restrict__ brm, const float* __restrict__ brv,
                     const float* __restrict__ compw, const float* __restrict__ compb,
                     __hip_bfloat16* __restrict__ feat_out) {
    const int b = blockIdx.x, tid = threadIdx.x;
    __shared__ float xs[T_ * 17];
    __shared__ float ybuf[24][T_];
    __shared__ float feat[TT][44];

    for (int i = tid; i < T_ * 17; i += 256) xs[i] = x[(long)b * T_ * 17 + i];
    __syncthreads();

    for (int i = tid; i < 24 * T_; i += 256) {
        int oc = i / T_, t = i % T_;
        float acc = cb[oc];
        #pragma unroll
        for (int kk = 0; kk < 3; ++kk) {
            int tt = t + kk - 1;
            if (tt >= 0 && tt < T_) {
                #pragma unroll
                for (int ic = 0; ic < 9; ++ic)
                    acc += xs[tt * 17 + ic] * cw[(oc * 9 + ic) * 3 + kk];
            }
        }
        acc = fmaxf(acc, 0.f);
        acc = (acc - brm[oc]) * rsqrtf(brv[oc] + EPSF) * bg[oc] + bb[oc];
        ybuf[oc][t] = acc;
    }
    __syncthreads();

    for (int i = tid; i < TT * 24; i += 256) {
        int u = i / 24, oc = i % 24;
        feat[u][oc] = fmaxf(ybuf[oc][2 * u], ybuf[oc][2 * u + 1]);
    }
    for (int i = tid; i < TT * 20; i += 256) {
        int u = i / 20, oc = i % 20;
        float acc = compb[oc];
        #pragma unroll
        for (int j = 0; j < 8; ++j) acc += xs[u * 17 + 9 + j] * compw[oc * 8 + j];
        feat[u][24 + oc] = fmaxf(acc, 0.f);
    }
    __syncthreads();

    for (int i = tid; i < TT * FEATK; i += 256) {
        int u = i >> 6, c = i & 63;
        float v = (c < 44) ? feat[u][c] : 0.f;
        feat_out[((long)b * TT + u) * FEATK + c] = __float2bfloat16(v);
    }
}

// ---------------------------------------------------------------------------
// bf16 MFMA GEMM core (BK=64, proven) — kept for the attention chain.
// ---------------------------------------------------------------------------
template <int WRITE_BF16>
__device__ __forceinline__
void gemm_core(const __hip_bfloat16* __restrict__ A0, int lda0,
               const __hip_bfloat16* __restrict__ A1, int lda1, int ksplit,
               const __hip_bfloat16* __restrict__ W, int ldw,
               const float* __restrict__ bias,
               void* __restrict__ Cout, int ldc, int K, int bx, int by) {
    __shared__ __hip_bfloat16 As[128 * 64];
    __shared__ __hip_bfloat16 Bs[128 * 64];
    const int tid = threadIdx.x;
    const int wave = tid >> 6, lane = tid & 63;
    const long m0 = (long)by * 128;
    const long n0 = (long)bx * 128;

    f32x4 acc[4][4] = {};

    for (int k0 = 0; k0 < K; k0 += 64) {
        __syncthreads();
        #pragma unroll
        for (int it = 0; it < 4; ++it) {
            int id = it * 256 + tid;
            int row = id >> 3;
            int kc = ((id & 7) ^ (row & 7)) << 3;
            int gk = k0 + kc;
            const __hip_bfloat16* srcA;
            if (gk < ksplit) srcA = A0 + (m0 + row) * (long)lda0 + gk;
            else             srcA = A1 + (m0 + row) * (long)lda1 + (gk - ksplit);
            async_load16(srcA, &As[id * 8]);
            const __hip_bfloat16* srcB = W + (n0 + row) * (long)ldw + gk;
            async_load16(srcB, &Bs[id * 8]);
        }
        __syncthreads();
        #pragma unroll
        for (int ks = 0; ks < 2; ++ks) {
            const int kb = ((ks * 4 + (lane >> 4)) ^ (lane & 7)) << 3;
            const int ar = (wave >> 1) * 64 + (lane & 15);
            const int br = (wave & 1) * 64 + (lane & 15);
            bf16x8 afr[4], bfr[4];
            #pragma unroll
            for (int i = 0; i < 4; ++i) afr[i] = *(const bf16x8*)&As[(ar + i * 16) * 64 + kb];
            #pragma unroll
            for (int i = 0; i < 4; ++i) bfr[i] = *(const bf16x8*)&Bs[(br + i * 16) * 64 + kb];
            #pragma unroll
            for (int mi = 0; mi < 4; ++mi)
                #pragma unroll
                for (int ni = 0; ni < 4; ++ni)
                    acc[mi][ni] = __builtin_amdgcn_mfma_f32_16x16x32_bf16(afr[mi], bfr[ni], acc[mi][ni], 0, 0, 0);
        }
    }

    const int cr = (lane >> 4) * 4;
    const int ccol = lane & 15;
    #pragma unroll
    for (int ni = 0; ni < 4; ++ni) {
        long col = n0 + (wave & 1) * 64 + ni * 16 + ccol;
        float bv = bias ? bias[col] : 0.f;
        #pragma unroll
        for (int mi = 0; mi < 4; ++mi) {
            long rowb = m0 + (wave >> 1) * 64 + mi * 16 + cr;
            #pragma unroll
            for (int r = 0; r < 4; ++r) {
                float v = acc[mi][ni][r] + bv;
                if (WRITE_BF16)
                    ((__hip_bfloat16*)Cout)[(rowb + r) * (long)ldc + col] = __float2bfloat16(v);
                else
                    ((float*)Cout)[(rowb + r) * (long)ldc + col] = v;
            }
        }
    }
}

template <int WRITE_BF16>
__global__ __launch_bounds__(256)
void gemm_bias(const __hip_bfloat16* __restrict__ A0, int lda0,
               const __hip_bfloat16* __restrict__ A1, int lda1, int ksplit,
               const __hip_bfloat16* __restrict__ W, int ldw,
               const float* __restrict__ bias,
               void* __restrict__ Cout, int ldc, int K) {
    gemm_core<WRITE_BF16>(A0, lda0, A1, lda1, ksplit, W, ldw, bias, Cout, ldc, K,
                          blockIdx.x, blockIdx.y);
}

// ---------------------------------------------------------------------------
// R22 fused gate GEMM = R19 core (best verified: 128x80 tile, 4 waves, BK=64
// full-LDS dbuf, hoisted it-invariant staging addresses, 2048-block grid)
// with the o/tanh(c) handoff in IEEE f16 (__half) instead of f32.
// Numerics: R13's bf16 handoff failed at absmax 0.0195 (bf16 abs err ~1e-3
// amplified by 1/std in the LN). f16 has 8x finer mantissa for |x|<2 ->
// predicted added error ~0.002, total ~0.006 < 0.0093 threshold.
// Traffic: handoff 32 MB/step -> 16 MB/step written + same saved on the
// gate_ln re-read (~27% of the scan's HBM volume).
// ---------------------------------------------------------------------------
__device__ __forceinline__
void fused_gate_core(const __hip_bfloat16* __restrict__ A0, int lda0,
                     const __hip_bfloat16* __restrict__ A1, int lda1,
                     int ksplit, int K,
                     const __hip_bfloat16* __restrict__ Wp, int ldw,
                     const float* __restrict__ bias,
                     const float* __restrict__ ret,
                     float* __restrict__ c_t,
                     __half* __restrict__ opre,
                     __half* __restrict__ tcn,
                     int m, int nblk) {
    __shared__ __hip_bfloat16 As[2][128 * 64];
    __shared__ __hip_bfloat16 Bs[2][80 * 64];
    const int tid = threadIdx.x;
    const int wave = tid >> 6, lane = tid & 63;
    const long m0 = (long)m * 128;
    const int n0row = nblk * 80;
    const int jbase = nblk * 16;
    const int rsel = lane & 15;
    const int q = lane >> 4;

    // Hoisted staging addresses (it-invariant swizzle).
    const int kc = ((tid & 7) ^ ((tid >> 3) & 7)) << 3;
    const int srow = tid >> 3;                       // 0..31
    const __hip_bfloat16* pA0_t = A0 + (m0 + srow) * (long)lda0 + kc;
    const __hip_bfloat16* pA1_t =
        A1 ? (A1 + (m0 + srow) * (long)lda1 + kc - ksplit) : pA0_t;
    const __hip_bfloat16* pB_t = Wp + (long)(n0row + srow) * ldw + kc;
    const int ks_slab = ksplit >> 6;
    const int nslab = K >> 6;

    auto stage = [&](int hb, int kk) {
        const long koff = (long)kk << 6;
        const __hip_bfloat16* pa;
        long la;
        if (kk < ks_slab) { pa = pA0_t; la = lda0; }
        else              { pa = pA1_t; la = lda1; }
        #pragma unroll
        for (int it = 0; it < 4; ++it)
            async_load16(pa + (long)it * 32 * la + koff,
                         &As[hb][it * 2048 + tid * 8]);
        #pragma unroll
        for (int it = 0; it < 2; ++it)
            async_load16(pB_t + (long)it * 32 * ldw + koff,
                         &Bs[hb][it * 2048 + tid * 8]);
        if (tid < 128)
            async_load16(pB_t + (long)64 * ldw + koff,
                         &Bs[hb][4096 + tid * 8]);
    };

    stage(0, 0);
    f32x4 acc[2][5] = {};

    for (int kk = 0; kk < nslab; ++kk) {
        const int hb = kk & 1;
        __syncthreads();
        if (kk + 1 < nslab) stage(hb ^ 1, kk + 1);
        #pragma unroll
        for (int ks = 0; ks < 2; ++ks) {
            const int kb = ((ks * 4 + q) ^ (lane & 7)) << 3;
            bf16x8 afr[2], bfr[5];
            #pragma unroll
            for (int i = 0; i < 2; ++i)
                afr[i] = *(const bf16x8*)&As[hb][(wave * 32 + i * 16 + rsel) * 64 + kb];
            #pragma unroll
            for (int i = 0; i < 5; ++i)
                bfr[i] = *(const bf16x8*)&Bs[hb][(i * 16 + rsel) * 64 + kb];
            #pragma unroll
            for (int mi = 0; mi < 2; ++mi)
                #pragma unroll
                for (int ni = 0; ni < 5; ++ni)
                    acc[mi][ni] = __builtin_amdgcn_mfma_f32_16x16x32_bf16(bfr[ni], afr[mi], acc[mi][ni], 0, 0, 0);
        }
    }

    // Fused epilogue: per thread 2 b-rows x 4 j; f16 packed 8B stores.
    #pragma unroll
    for (int mi = 0; mi < 2; ++mi) {
        const long b = m0 + wave * 32 + mi * 16 + rsel;
        sh4 ov, tv;
        #pragma unroll
        for (int r = 0; r < 4; ++r) {
            const int jg = jbase + 4 * q + r;
            float f  = sigmoidf_(acc[mi][0][r] + bias[jg]);
            float ii = sigmoidf_(acc[mi][1][r] + bias[512 + jg]);
            float o  = sigmoidf_(acc[mi][2][r] + bias[1024 + jg]);
            float cc = tanhf(acc[mi][3][r] + bias[1536 + jg]);
            float mg = sigmoidf_(acc[mi][4][r] + bias[2048 + jg]);
            float cold = c_t[(long)jg * B_ + b];
            float rr = ret[jg];
            float cn = f * cold + ii * cc;
            cn = cn * rr + (1.f - rr) * cold;
            cn = mg * cn + (1.f - mg) * cold;
            c_t[(long)jg * B_ + b] = cn;
            __half oh = __float2half(o);
            __half th = __float2half(tanhf(cn));
            ov[r] = *(short*)&oh;
            tv[r] = *(short*)&th;
        }
        *(sh4*)&opre[b * H_ + jbase + 4 * q] = ov;
        *(sh4*)&tcn [b * H_ + jbase + 4 * q] = tv;
    }
}

// Single-layer wrapper (boundary steps). grid = 1024 (32 m x 32 n), XCD-grouped.
__global__ __launch_bounds__(256)
void fused_gate_single(const __hip_bfloat16* A0, int lda0, const __hip_bfloat16* A1,
                       int lda1, int ksplit, int K,
                       const __hip_bfloat16* Wp, int ldw,
                       const float* bias, const float* ret, float* c_t,
                       __half* opre, __half* tcn) {
    const int id = blockIdx.x;
    const int xcd = id & 7;
    const int rest = id >> 3;                 // [0,128)
    const int m = xcd * 4 + (rest & 3);
    const int n = (rest >> 2) & 31;
    fused_gate_core(A0, lda0, A1, lda1, ksplit, K, Wp, ldw, bias, ret, c_t,
                    opre, tcn, m, n);
}

// Dual-layer wrapper. grid = 2048: xcd=id&7; rest bits [0:1]=m-sub, [2:6]=n, [7]=z.
__global__ __launch_bounds__(256)
void fused_gate_dual(const __hip_bfloat16* A0a, int lda0a, const __hip_bfloat16* A1a,
                     int lda1a, int ksplita, int Ka,
                     const __hip_bfloat16* Wpa, int ldwa,
                     const float* biasa, const float* reta, float* cta,
                     __half* oprea, __half* tcna,
                     const __hip_bfloat16* A0b, int lda0b, const __hip_bfloat16* A1b,
                     int lda1b, int ksplitb, int Kb,
                     const __hip_bfloat16* Wpb, int ldwb,
                     const float* biasb, const float* retb, float* ctb,
                     __half* opreb, __half* tcnb) {
    const int id = blockIdx.x;
    const int xcd = id & 7;
    const int rest = id >> 3;                 // [0,256)
    const int m = xcd * 4 + (rest & 3);
    const int n = (rest >> 2) & 31;
    const int z = rest >> 7;
    if (z == 0)
        fused_gate_core(A0a, lda0a, A1a, lda1a, ksplita, Ka, Wpa, ldwa,
                        biasa, reta, cta, oprea, tcna, m, n);
    else
        fused_gate_core(A0b, lda0b, A1b, lda1b, ksplitb, Kb, Wpb, ldwb,
                        biasb, retb, ctb, opreb, tcnb, m, n);
}

// ---------------------------------------------------------------------------
// gate_ln: the two LayerNorms (need full-j stats) on f16 o/tanh(c).
// ---------------------------------------------------------------------------
__device__ __forceinline__ void block_reduce2(float& a, float& b, float* red) {
    #pragma unroll
    for (int off = 32; off > 0; off >>= 1) {
        a += __shfl_down(a, off, 64);
        b += __shfl_down(b, off, 64);
    }
    int lane = threadIdx.x & 63, w = threadIdx.x >> 6;
    if (lane == 0) { red[w] = a; red[8 + w] = b; }
    __syncthreads();
    a = red[0] + red[1] + red[2] + red[3];
    b = red[8] + red[9] + red[10] + red[11];
    __syncthreads();
}

__device__ __forceinline__
void gate_ln_body(const __half* __restrict__ opre,
                  const __half* __restrict__ tcn,
                  const float* __restrict__ elg, const float* __restrict__ elb,
                  const float* __restrict__ lng, const float* __restrict__ lnb,
                  __hip_bfloat16* __restrict__ hout, long hstride, int b) {
    const int tid = threadIdx.x;
    __shared__ float red[16];

    float o_[2], t_[2];
    float s = 0.f, s2 = 0.f;
    #pragma unroll
    for (int u = 0; u < 2; ++u) {
        int j = tid + u * 256;
        float o = __half2float(opre[(long)b * H_ + j]);
        float t = __half2float(tcn[(long)b * H_ + j]);
        o_[u] = o; t_[u] = t;
        s += o; s2 += o * o;
    }
    block_reduce2(s, s2, red);
    float mean = s * (1.f / H_);
    float var = s2 * (1.f / H_) - mean * mean;
    float rstd = rsqrtf(var + EPSF);

    float val[2];
    float s3 = 0.f, s4 = 0.f;
    #pragma unroll
    for (int u = 0; u < 2; ++u) {
        int j = tid + u * 256;
        float on = (o_[u] - mean) * rstd * elg[j] + elb[j];
        float v = sigmoidf_(on) * t_[u];
        val[u] = v; s3 += v; s4 += v * v;
    }
    block_reduce2(s3, s4, red);
    float mean2 = s3 * (1.f / H_);
    float var2 = s4 * (1.f / H_) - mean2 * mean2;
    float rstd2 = rsqrtf(var2 + EPSF);
    #pragma unroll
    for (int u = 0; u < 2; ++u) {
        int j = tid + u * 256;
        float h = (val[u] - mean2) * rstd2 * lng[j] + lnb[j];
        hout[(long)b * hstride + j] = __float2bfloat16(h);
    }
}

__global__ __launch_bounds__(256)
void gate_ln(const __half* __restrict__ opre,
             const __half* __restrict__ tcn,
             const float* __restrict__ elg, const float* __restrict__ elb,
             const float* __restrict__ lng, const float* __restrict__ lnb,
             __hip_bfloat16* __restrict__ hout, long hstride) {
    gate_ln_body(opre, tcn, elg, elb, lng, lnb, hout, hstride, blockIdx.x);
}

__global__ __launch_bounds__(256)
void gate_ln_dual(const __half* oa, const __half* ta,
                  const float* elga, const float* elba,
                  const float* lnga, const float* lnba,
                  __hip_bfloat16* houta, long hstridea,
                  const __half* ob, const __half* tb,
                  const float* elgb, const float* elbb,
                  const float* lngb, const float* lnbb,
                  __hip_bfloat16* houtb, long hstrideb) {
    int bid = blockIdx.x;
    bool isB = bid >= B_;
    int b = isB ? bid - B_ : bid;
    gate_ln_body(isB ? ob : oa, isB ? tb : ta,
                 isB ? elgb : elga, isB ? elbb : elba,
                 isB ? lngb : lnga, isB ? lnbb : lnba,
                 isB ? houtb : houta, isB ? hstrideb : hstridea, b);
}

// ---------------------------------------------------------------------------
// R11 fused attention (unchanged).
// ---------------------------------------------------------------------------
__global__ __launch_bounds__(256)
void attn_fused(const __hip_bfloat16* __restrict__ seq,
                const __hip_bfloat16* __restrict__ U,
                __hip_bfloat16* __restrict__ sbar) {
    const int b = blockIdx.x, tid = threadIdx.x;
    const int h = tid >> 6, lane = tid & 63;
    const int c0 = lane * 8;
    __shared__ float ps[NH_ * TT];      // 480 B
    const float scale = 0.08838834764831845f;   // 1/sqrt(128)

    float uq[8];
    {
        bf16x8 uv = *(const bf16x8*)&U[(size_t)b * (NH_ * H_) + h * H_ + c0];
        for (int j = 0; j < 8; ++j) uq[j] = bf2f(uv[j]);
    }
    const __hip_bfloat16* srow = seq + (size_t)b * TT * H_;

    for (int t = 0; t < TT; ++t) {
        bf16x8 sv = *(const bf16x8*)&srow[t * H_ + c0];
        float a = 0.f;
        for (int j = 0; j < 8; ++j) a += uq[j] * bf2f(sv[j]);
        a += __shfl_xor(a, 32);
        a += __shfl_xor(a, 16);
        a += __shfl_xor(a, 8);
        a += __shfl_xor(a, 4);
        a += __shfl_xor(a, 2);
        a += __shfl_xor(a, 1);
        if (lane == 0) ps[h * TT + t] = a * scale;
    }
    __syncthreads();

    float mx = -1e30f;
    for (int t = 0; t < TT; ++t) mx = fmaxf(mx, ps[h * TT + t]);
    float den = 0.f;
    for (int t = 0; t < TT; ++t) den += __expf(ps[h * TT + t] - mx);
    float inv = 1.f / den;

    float accv[8];
    for (int j = 0; j < 8; ++j) accv[j] = 0.f;
    for (int t = 0; t < TT; ++t) {
        float w = __expf(ps[h * TT + t] - mx) * inv;
        bf16x8 sv = *(const bf16x8*)&srow[t * H_ + c0];
        for (int j = 0; j < 8; ++j) accv[j] += w * bf2f(sv[j]);
    }
    bf16x8 outv;
    for (int j = 0; j < 8; ++j) {
        __hip_bfloat16 hv = __float2bfloat16(accv[j]);
        outv[j] = *(short*)&hv;
    }
    *(bf16x8*)&sbar[(size_t)b * (NH_ * H_) + h * H_ + c0] = outv;
}

// ---------------------------------------------------------------------------
// Head (unchanged).
// ---------------------------------------------------------------------------
__global__ __launch_bounds__(128)
void head_kernel(const float* __restrict__ lat_in,
                 const float* __restrict__ g2, const float* __restrict__ b2,
                 const float* __restrict__ rm2, const float* __restrict__ rv2,
                 const float* __restrict__ ow, const float* __restrict__ ob,
                 float* __restrict__ out) {
    const int b = blockIdx.x, tid = threadIdx.x;
    __shared__ float ls[LAT_];
    float a = lat_in[(long)b * LAT_ + tid];
    ls[tid] = (a - rm2[tid]) * rsqrtf(rv2[tid] + EPSF) * g2[tid] + b2[tid];
    __syncthreads();
    if (tid < OUT_) {
        float acc = ob[tid];
        #pragma unroll 4
        for (int j = 0; j < LAT_; ++j) acc += ls[j] * ow[tid * LAT_ + j];
        out[(long)b * OUT_ + tid] = acc;
    }
}

// ---------------------------------------------------------------------------
extern "C" void kernel_launch(void* const* d_in, const int* in_sizes, int n_in,
                              void* d_out, int out_size, void* d_ws, size_t ws_size,
                              hipStream_t stream) {
    const float* x        = (const float*)d_in[0];
    const float* conv1_w  = (const float*)d_in[1];
    const float* conv1_b  = (const float*)d_in[2];
    const float* bn1_g    = (const float*)d_in[3];
    const float* bn1_b    = (const float*)d_in[4];
    const float* bn1_rm   = (const float*)d_in[5];
    const float* bn1_rv   = (const float*)d_in[6];
    const float* comp_w   = (const float*)d_in[7];
    const float* comp_b   = (const float*)d_in[8];
    const float* proj_w   = (const float*)d_in[9];
    const float* proj_b   = (const float*)d_in[10];
    const float* gates_w  = (const float*)d_in[11];
    const float* gates_b  = (const float*)d_in[12];
    const float* retention= (const float*)d_in[13];
    const float* expln_g  = (const float*)d_in[14];
    const float* expln_b  = (const float*)d_in[15];
    const float* ln_g     = (const float*)d_in[16];
    const float* ln_b     = (const float*)d_in[17];
    const float* attn_in_w  = (const float*)d_in[18];
    const float* attn_in_b  = (const float*)d_in[19];
    const float* attn_out_w = (const float*)d_in[20];
    const float* attn_out_b = (const float*)d_in[21];
    const float* bneck_w  = (const float*)d_in[22];
    const float* bneck_b  = (const float*)d_in[23];
    const float* bn2_g    = (const float*)d_in[24];
    const float* bn2_b    = (const float*)d_in[25];
    const float* bn2_rm   = (const float*)d_in[26];
    const float* bn2_rv   = (const float*)d_in[27];
    const float* out_w    = (const float*)d_in[28];
    const float* out_b    = (const float*)d_in[29];
    float* out = (float*)d_out;

    // ---- workspace layout (~230 MiB) ----
    char* base = (char*)d_ws;
    size_t off = 0;
    auto alloc = [&](size_t nbytes) -> char* {
        char* p = base + off;
        off += (nbytes + 255) & ~(size_t)255;
        return p;
    };
    __hip_bfloat16* seq_bf = (__hip_bfloat16*)alloc((size_t)B_ * TT * H_ * 2);   // 126 MB
    // union (42 MB): scan f16 o/tanh x2 layers (16 MB) / attn U+sbar+wkd+wvd
    size_t g_bytes = (size_t)B_ * NGATE_ * 2;                                    // 21 MB
    char* un = alloc(2 * g_bytes);
    __half* opreA = (__half*)un;                                   // 4 MB (layer1)
    __half* tcnA  = (__half*)(un + (size_t)4 * 1024 * 1024);
    __half* opreB = (__half*)(un + (size_t)8 * 1024 * 1024);       // layer0
    __half* tcnB  = (__half*)(un + (size_t)12 * 1024 * 1024);
    __hip_bfloat16* U_bf    = (__hip_bfloat16*)un;                               // attn phase
    __hip_bfloat16* sbar_bf = (__hip_bfloat16*)(un + (size_t)16 * 1024 * 1024);
    __hip_bfloat16* wkd_bf  = (__hip_bfloat16*)(un + (size_t)32 * 1024 * 1024);
    __hip_bfloat16* wvd_bf  = (__hip_bfloat16*)(un + (size_t)35 * 1024 * 1024);
    __hip_bfloat16* feat_bf = (__hip_bfloat16*)alloc((size_t)B_ * TT * FEATK * 2); // 15.7 MB
    float*          c0t   = (float*)alloc((size_t)B_ * H_ * 4);   // transposed [j][B]
    float*          c1t   = (float*)alloc((size_t)B_ * H_ * 4);
    __hip_bfloat16* h0_bf = (__hip_bfloat16*)alloc((size_t)B_ * H_ * 2);
    __hip_bfloat16* q_bf  = (__hip_bfloat16*)alloc((size_t)B_ * H_ * 2);  // also fin
    __hip_bfloat16* fin_bf = q_bf;
    __hip_bfloat16* av_bf = (__hip_bfloat16*)alloc((size_t)B_ * H_ * 2);
    float*          lat_f = (float*)alloc((size_t)B_ * LAT_ * 4);
    __hip_bfloat16* w1p_bf = (__hip_bfloat16*)alloc((size_t)NGATE_ * 2 * H_ * 2); // 5.24 MB
    __hip_bfloat16* w0p_bf = (__hip_bfloat16*)alloc((size_t)NGATE_ * K0M * 2);    // 2.95 MB
    float*          bc_f  = (float*)alloc((size_t)NGATE_ * 4);
    __hip_bfloat16* ai_bf = (__hip_bfloat16*)alloc((size_t)H_ * H_ * 2);
    __hip_bfloat16* ao_bf = (__hip_bfloat16*)alloc((size_t)H_ * H_ * 2);
    __hip_bfloat16* bw_bf = (__hip_bfloat16*)alloc((size_t)LAT_ * H_ * 2);
    (void)ws_size; (void)in_sizes; (void)n_in; (void)out_size;

    // ---- weight conversion / composition / permutation + state zeroing ----
    const int WL = 5 * H_ * 2 * H_;
    perm_w1<<<(NGATE_ * 2 * H_) / 256, 256, 0, stream>>>(gates_w + WL, w1p_bf);
    build_w0m<<<NGATE_ / 4, 256, 0, stream>>>(gates_w, proj_w, proj_b, gates_b,
                                              w0p_bf, bc_f);
    cvt_bf16<<<256, 256, 0, stream>>>(attn_in_w, ai_bf, (long)H_ * H_);
    cvt_bf16<<<256, 256, 0, stream>>>(attn_out_w, ao_bf, (long)H_ * H_);
    cvt_bf16<<<64, 256, 0, stream>>>(bneck_w, bw_bf, (long)LAT_ * H_);
    zero_f32<<<2048, 256, 0, stream>>>(c0t, (long)2 * B_ * H_);   // c0t+c1t contiguous

    // ---- front-end: feat only (proj composed into layer0 weights) ----
    frontend_kernel<<<B_, 256, 0, stream>>>(x, conv1_w, conv1_b, bn1_g, bn1_b, bn1_rm,
                                            bn1_rv, comp_w, comp_b, feat_bf);

    // ---- recurrent scan (layer1(t) || layer0(t+1) dual pipeline) ----
    // layer0 @ t=0: K=64 (composed feat cols only; h=0)
    fused_gate_single<<<1024, 256, 0, stream>>>(
        feat_bf, TT * FEATK, (const __hip_bfloat16*)nullptr, 0, FEATK, FEATK,
        w0p_bf, K0M, bc_f, retention, c0t, opreB, tcnB);
    gate_ln<<<B_, 256, 0, stream>>>(opreB, tcnB, expln_g, expln_b,
                                    ln_g, ln_b, h0_bf, H_);

    for (int t = 0; t < TT - 1; ++t) {
        fused_gate_dual<<<2048, 256, 0, stream>>>(
            // z0 = layer1(t): K = t? 1024 : 512 (h1(-1)=0), ksplit 512
            h0_bf, H_, (t == 0) ? (const __hip_bfloat16*)nullptr
                                : seq_bf + (size_t)(t - 1) * H_,
            TT * H_, H_, (t == 0) ? H_ : 2 * H_,
            w1p_bf, 2 * H_, gates_b + NGATE_, retention + H_, c1t, opreA, tcnA,
            // z1 = layer0(t+1): K = 576 (64 composed feat + 512 h), ksplit 64
            feat_bf + (size_t)(t + 1) * FEATK, TT * FEATK, h0_bf, H_, FEATK, K0M,
            w0p_bf, K0M, bc_f, retention, c0t, opreB, tcnB);
        gate_ln_dual<<<2 * B_, 256, 0, stream>>>(
            opreA, tcnA, expln_g + H_, expln_b + H_, ln_g + H_, ln_b + H_,
            seq_bf + (size_t)t * H_, TT * H_,
            opreB, tcnB, expln_g, expln_b, ln_g, ln_b, h0_bf, H_);
    }
    // layer1 @ t=29
    fused_gate_single<<<1024, 256, 0, stream>>>(
        h0_bf, H_, seq_bf + (size_t)(TT - 2) * H_, TT * H_, H_, 2 * H_,
        w1p_bf, 2 * H_, gates_b + NGATE_, retention + H_, c1t, opreA, tcnA);
    gate_ln<<<B_, 256, 0, stream>>>(opreA, tcnA, expln_g + H_, expln_b + H_,
                                    ln_g + H_, ln_b + H_,
                                    seq_bf + (size_t)(TT - 1) * H_, TT * H_);

    // ---- attention (unchanged) ----
    build_wkd<<<4096, 256, 0, stream>>>(attn_in_w, wkd_bf);
    build_wvd<<<4096, 256, 0, stream>>>(attn_in_w, wvd_bf);

    gemm_bias<1><<<dim3(H_ / 128, B_ / 128), 256, 0, stream>>>(
        seq_bf + (size_t)29 * H_, TT * H_, (const __hip_bfloat16*)nullptr, 0, H_,
        ai_bf, H_, attn_in_b, (void*)q_bf, H_, H_);

    gemm_bias<1><<<dim3(2048 / 128, B_ / 128), 256, 0, stream>>>(
        q_bf, H_, (const __hip_bfloat16*)nullptr, 0, H_,
        wkd_bf, H_, (const float*)nullptr, (void*)U_bf, 2048, H_);

    attn_fused<<<B_, 256, 0, stream>>>(seq_bf, U_bf, sbar_bf);

    gemm_bias<1><<<dim3(H_ / 128, B_ / 128), 256, 0, stream>>>(
        sbar_bf, 2048, (const __hip_bfloat16*)nullptr, 0, 2048,
        wvd_bf, 2048, attn_in_b + 2 * H_, (void*)av_bf, H_, 2048);

    gemm_bias<1><<<dim3(H_ / 128, B_ / 128), 256, 0, stream>>>(
        av_bf, H_, (const __hip_bfloat16*)nullptr, 0, H_,
        ao_bf, H_, attn_out_b, (void*)fin_bf, H_, H_);

    gemm_bias<0><<<dim3(LAT_ / 128, B_ / 128), 256, 0, stream>>>(
        fin_bf, H_, (const __hip_bfloat16*)nullptr, 0, H_,
        bw_bf, H_, bneck_b, (void*)lat_f, LAT_, H_);
    head_kernel<<<B_, 128, 0, stream>>>(lat_f, bn2_g, bn2_b, bn2_rm, bn2_rv,
                                        out_w, out_b, out);
}

// Round 13
// 2382.070 us; speedup vs baseline: 1.1701x; 1.0258x over previous
//
#include <hip/hip_runtime.h>
#include <hip/hip_bf16.h>
#include <hip/hip_fp16.h>

// Problem constants
#define B_   4096
#define T_   60
#define TT   30          // pooled sequence length
#define H_   512
#define L_   2
#define NH_  4
#define DH_  128
#define LAT_ 128
#define OUT_ 14
#define NGATE_ (5*H_)    // 2560
#define EPSF 1e-5f
#define FEATK 64         // feat padded to 64 (GEMM K granularity)
#define K0M  (FEATK + H_)   // 576: layer0 merged K (composed feat + h)

typedef __attribute__((ext_vector_type(8))) short bf16x8;
typedef __attribute__((ext_vector_type(4))) short sh4;     // 4 x 16-bit
typedef __attribute__((ext_vector_type(4))) float f32x4;

__device__ __forceinline__ float sigmoidf_(float x) { return 1.0f / (1.0f + __expf(-x)); }
__device__ __forceinline__ float bf2f(short s) {
    return __uint_as_float(((unsigned)(unsigned short)s) << 16);
}

__device__ __forceinline__ void async_load16(const void* g, void* l) {
    __builtin_amdgcn_global_load_lds((const __attribute__((address_space(1))) void*)g,
                                     (__attribute__((address_space(3))) void*)l, 16, 0, 0);
}

// Gate-row permutation: original n = g*512 + j  ->  n' = (j>>4)*80 + g*16 + (j&15).
__device__ __forceinline__ int perm_row(int n) {
    int g = n >> 9, j = n & 511;
    return (j >> 4) * 80 + g * 16 + (j & 15);
}

// ---------------------------------------------------------------------------
// Utility kernels
// ---------------------------------------------------------------------------
__global__ __launch_bounds__(256) void cvt_bf16(const float* __restrict__ in,
                                                __hip_bfloat16* __restrict__ out, long n) {
    long i = (long)blockIdx.x * blockDim.x + threadIdx.x;
    long stride = (long)gridDim.x * blockDim.x;
    for (; i < n; i += stride) out[i] = __float2bfloat16(in[i]);
}

__global__ __launch_bounds__(256) void zero_f32(float* __restrict__ p, long n) {
    long i = (long)blockIdx.x * blockDim.x + threadIdx.x;
    long stride = (long)gridDim.x * blockDim.x;
    for (; i < n; i += stride) p[i] = 0.0f;
}

// layer1 gate weights f32 -> bf16, rows permuted for the fused kernel
__global__ __launch_bounds__(256)
void perm_w1(const float* __restrict__ gw, __hip_bfloat16* __restrict__ w1p) {
    long i = (long)blockIdx.x * 256 + threadIdx.x;       // 2560*1024
    if (i >= (long)NGATE_ * 2 * H_) return;
    int n = (int)(i >> 10), k = (int)(i & 1023);
    w1p[(long)perm_row(n) * (2 * H_) + k] = __float2bfloat16(gw[i]);
}

// Compose proj into layer0's input weights; rows permuted.
__global__ __launch_bounds__(256)
void build_w0m(const float* __restrict__ gw, const float* __restrict__ pw,
               const float* __restrict__ pb, const float* __restrict__ gb,
               __hip_bfloat16* __restrict__ w0p, float* __restrict__ bc) {
    const int tid = threadIdx.x;
    const int n = blockIdx.x * 4 + (tid >> 6);   // 640 blocks * 4 = 2560 rows
    const int f = tid & 63;
    const long np = perm_row(n);
    const float* wrow = gw + (long)n * (2 * H_);  // layer0 gate row [1024]
    float acc = 0.f;
    if (f < 44) {
        for (int k = 0; k < H_; ++k) acc += wrow[k] * pw[k * 44 + f];
    }
    w0p[np * K0M + f] = __float2bfloat16(acc);
    #pragma unroll
    for (int j = 0; j < 8; ++j) {
        int col = f * 8 + j;
        w0p[np * K0M + FEATK + col] = __float2bfloat16(wrow[H_ + col]);
    }
    float s = 0.f;
    #pragma unroll
    for (int j = 0; j < 8; ++j) s += wrow[f * 8 + j] * pb[f * 8 + j];
    #pragma unroll
    for (int off = 32; off > 0; off >>= 1) s += __shfl_down(s, off, 64);
    if (f == 0) bc[n] = gb[n] + s;
}

// R23: compact per-head K-weight transpose: wkt[h*512+j][k] = Wk[h*128+k][j].
// U_h = q_h[4096x128] @ wkt_h^T -> exact same sums as the old zero-padded
// wkd GEMM (removed terms are exact zeros), at 1/4 the K.
__global__ __launch_bounds__(256)
void build_wkt(const float* __restrict__ aiw, __hip_bfloat16* __restrict__ wkt) {
    int i = blockIdx.x * 256 + threadIdx.x;          // 2048*128
    if (i >= 2048 * 128) return;
    int row = i >> 7;            // h*512 + j
    int k = i & 127;
    int h = row >> 9, j = row & 511;
    wkt[i] = __float2bfloat16(aiw[(H_ + h * 128 + k) * H_ + j]);
}

// ---------------------------------------------------------------------------
// Front-end (unchanged)
// ---------------------------------------------------------------------------
__global__ __launch_bounds__(256)
void frontend_kernel(const float* __restrict__ x,
                     const float* __restrict__ cw, const float* __restrict__ cb,
                     const float* __restrict__ bg, const float* __restrict__ bb,
                     const float* __restrict__ brm, const float* __restrict__ brv,
                     const float* __restrict__ compw, const float* __restrict__ compb,
                     __hip_bfloat16* __restrict__ feat_out) {
    const int b = blockIdx.x, tid = threadIdx.x;
    __shared__ float xs[T_ * 17];
    __shared__ float ybuf[24][T_];
    __shared__ float feat[TT][44];

    for (int i = tid; i < T_ * 17; i += 256) xs[i] = x[(long)b * T_ * 17 + i];
    __syncthreads();

    for (int i = tid; i < 24 * T_; i += 256) {
        int oc = i / T_, t = i % T_;
        float acc = cb[oc];
        #pragma unroll
        for (int kk = 0; kk < 3; ++kk) {
            int tt = t + kk - 1;
            if (tt >= 0 && tt < T_) {
                #pragma unroll
                for (int ic = 0; ic < 9; ++ic)
                    acc += xs[tt * 17 + ic] * cw[(oc * 9 + ic) * 3 + kk];
            }
        }
        acc = fmaxf(acc, 0.f);
        acc = (acc - brm[oc]) * rsqrtf(brv[oc] + EPSF) * bg[oc] + bb[oc];
        ybuf[oc][t] = acc;
    }
    __syncthreads();

    for (int i = tid; i < TT * 24; i += 256) {
        int u = i / 24, oc = i % 24;
        feat[u][oc] = fmaxf(ybuf[oc][2 * u], ybuf[oc][2 * u + 1]);
    }
    for (int i = tid; i < TT * 20; i += 256) {
        int u = i / 20, oc = i % 20;
        float acc = compb[oc];
        #pragma unroll
        for (int j = 0; j < 8; ++j) acc += xs[u * 17 + 9 + j] * compw[oc * 8 + j];
        feat[u][24 + oc] = fmaxf(acc, 0.f);
    }
    __syncthreads();

    for (int i = tid; i < TT * FEATK; i += 256) {
        int u = i >> 6, c = i & 63;
        float v = (c < 44) ? feat[u][c] : 0.f;
        feat_out[((long)b * TT + u) * FEATK + c] = __float2bfloat16(v);
    }
}

// ---------------------------------------------------------------------------
// bf16 MFMA GEMM core (BK=64, proven) — attention chain.
// ---------------------------------------------------------------------------
template <int WRITE_BF16>
__device__ __forceinline__
void gemm_core(const __hip_bfloat16* __restrict__ A0, int lda0,
               const __hip_bfloat16* __restrict__ A1, int lda1, int ksplit,
               const __hip_bfloat16* __restrict__ W, int ldw,
               const float* __restrict__ bias,
               void* __restrict__ Cout, int ldc, int K, int bx, int by) {
    __shared__ __hip_bfloat16 As[128 * 64];
    __shared__ __hip_bfloat16 Bs[128 * 64];
    const int tid = threadIdx.x;
    const int wave = tid >> 6, lane = tid & 63;
    const long m0 = (long)by * 128;
    const long n0 = (long)bx * 128;

    f32x4 acc[4][4] = {};

    for (int k0 = 0; k0 < K; k0 += 64) {
        __syncthreads();
        #pragma unroll
        for (int it = 0; it < 4; ++it) {
            int id = it * 256 + tid;
            int row = id >> 3;
            int kc = ((id & 7) ^ (row & 7)) << 3;
            int gk = k0 + kc;
            const __hip_bfloat16* srcA;
            if (gk < ksplit) srcA = A0 + (m0 + row) * (long)lda0 + gk;
            else             srcA = A1 + (m0 + row) * (long)lda1 + (gk - ksplit);
            async_load16(srcA, &As[id * 8]);
            const __hip_bfloat16* srcB = W + (n0 + row) * (long)ldw + gk;
            async_load16(srcB, &Bs[id * 8]);
        }
        __syncthreads();
        #pragma unroll
        for (int ks = 0; ks < 2; ++ks) {
            const int kb = ((ks * 4 + (lane >> 4)) ^ (lane & 7)) << 3;
            const int ar = (wave >> 1) * 64 + (lane & 15);
            const int br = (wave & 1) * 64 + (lane & 15);
            bf16x8 afr[4], bfr[4];
            #pragma unroll
            for (int i = 0; i < 4; ++i) afr[i] = *(const bf16x8*)&As[(ar + i * 16) * 64 + kb];
            #pragma unroll
            for (int i = 0; i < 4; ++i) bfr[i] = *(const bf16x8*)&Bs[(br + i * 16) * 64 + kb];
            #pragma unroll
            for (int mi = 0; mi < 4; ++mi)
                #pragma unroll
                for (int ni = 0; ni < 4; ++ni)
                    acc[mi][ni] = __builtin_amdgcn_mfma_f32_16x16x32_bf16(afr[mi], bfr[ni], acc[mi][ni], 0, 0, 0);
        }
    }

    const int cr = (lane >> 4) * 4;
    const int ccol = lane & 15;
    #pragma unroll
    for (int ni = 0; ni < 4; ++ni) {
        long col = n0 + (wave & 1) * 64 + ni * 16 + ccol;
        float bv = bias ? bias[col] : 0.f;
        #pragma unroll
        for (int mi = 0; mi < 4; ++mi) {
            long rowb = m0 + (wave >> 1) * 64 + mi * 16 + cr;
            #pragma unroll
            for (int r = 0; r < 4; ++r) {
                float v = acc[mi][ni][r] + bv;
                if (WRITE_BF16)
                    ((__hip_bfloat16*)Cout)[(rowb + r) * (long)ldc + col] = __float2bfloat16(v);
                else
                    ((float*)Cout)[(rowb + r) * (long)ldc + col] = v;
            }
        }
    }
}

template <int WRITE_BF16>
__global__ __launch_bounds__(256)
void gemm_bias(const __hip_bfloat16* __restrict__ A0, int lda0,
               const __hip_bfloat16* __restrict__ A1, int lda1, int ksplit,
               const __hip_bfloat16* __restrict__ W, int ldw,
               const float* __restrict__ bias,
               void* __restrict__ Cout, int ldc, int K) {
    gemm_core<WRITE_BF16>(A0, lda0, A1, lda1, ksplit, W, ldw, bias, Cout, ldc, K,
                          blockIdx.x, blockIdx.y);
}

// ---------------------------------------------------------------------------
// R22 fused gate GEMM (proven best: f16 handoff, hoisted staging, BK=64).
// ---------------------------------------------------------------------------
__device__ __forceinline__
void fused_gate_core(const __hip_bfloat16* __restrict__ A0, int lda0,
                     const __hip_bfloat16* __restrict__ A1, int lda1,
                     int ksplit, int K,
                     const __hip_bfloat16* __restrict__ Wp, int ldw,
                     const float* __restrict__ bias,
                     const float* __restrict__ ret,
                     float* __restrict__ c_t,
                     __half* __restrict__ opre,
                     __half* __restrict__ tcn,
                     int m, int nblk) {
    __shared__ __hip_bfloat16 As[2][128 * 64];
    __shared__ __hip_bfloat16 Bs[2][80 * 64];
    const int tid = threadIdx.x;
    const int wave = tid >> 6, lane = tid & 63;
    const long m0 = (long)m * 128;
    const int n0row = nblk * 80;
    const int jbase = nblk * 16;
    const int rsel = lane & 15;
    const int q = lane >> 4;

    // Hoisted staging addresses (it-invariant swizzle).
    const int kc = ((tid & 7) ^ ((tid >> 3) & 7)) << 3;
    const int srow = tid >> 3;                       // 0..31
    const __hip_bfloat16* pA0_t = A0 + (m0 + srow) * (long)lda0 + kc;
    const __hip_bfloat16* pA1_t =
        A1 ? (A1 + (m0 + srow) * (long)lda1 + kc - ksplit) : pA0_t;
    const __hip_bfloat16* pB_t = Wp + (long)(n0row + srow) * ldw + kc;
    const int ks_slab = ksplit >> 6;
    const int nslab = K >> 6;

    auto stage = [&](int hb, int kk) {
        const long koff = (long)kk << 6;
        const __hip_bfloat16* pa;
        long la;
        if (kk < ks_slab) { pa = pA0_t; la = lda0; }
        else              { pa = pA1_t; la = lda1; }
        #pragma unroll
        for (int it = 0; it < 4; ++it)
            async_load16(pa + (long)it * 32 * la + koff,
                         &As[hb][it * 2048 + tid * 8]);
        #pragma unroll
        for (int it = 0; it < 2; ++it)
            async_load16(pB_t + (long)it * 32 * ldw + koff,
                         &Bs[hb][it * 2048 + tid * 8]);
        if (tid < 128)
            async_load16(pB_t + (long)64 * ldw + koff,
                         &Bs[hb][4096 + tid * 8]);
    };

    stage(0, 0);
    f32x4 acc[2][5] = {};

    for (int kk = 0; kk < nslab; ++kk) {
        const int hb = kk & 1;
        __syncthreads();
        if (kk + 1 < nslab) stage(hb ^ 1, kk + 1);
        #pragma unroll
        for (int ks = 0; ks < 2; ++ks) {
            const int kb = ((ks * 4 + q) ^ (lane & 7)) << 3;
            bf16x8 afr[2], bfr[5];
            #pragma unroll
            for (int i = 0; i < 2; ++i)
                afr[i] = *(const bf16x8*)&As[hb][(wave * 32 + i * 16 + rsel) * 64 + kb];
            #pragma unroll
            for (int i = 0; i < 5; ++i)
                bfr[i] = *(const bf16x8*)&Bs[hb][(i * 16 + rsel) * 64 + kb];
            #pragma unroll
            for (int mi = 0; mi < 2; ++mi)
                #pragma unroll
                for (int ni = 0; ni < 5; ++ni)
                    acc[mi][ni] = __builtin_amdgcn_mfma_f32_16x16x32_bf16(bfr[ni], afr[mi], acc[mi][ni], 0, 0, 0);
        }
    }

    // Fused epilogue: per thread 2 b-rows x 4 j; f16 packed 8B stores.
    #pragma unroll
    for (int mi = 0; mi < 2; ++mi) {
        const long b = m0 + wave * 32 + mi * 16 + rsel;
        sh4 ov, tv;
        #pragma unroll
        for (int r = 0; r < 4; ++r) {
            const int jg = jbase + 4 * q + r;
            float f  = sigmoidf_(acc[mi][0][r] + bias[jg]);
            float ii = sigmoidf_(acc[mi][1][r] + bias[512 + jg]);
            float o  = sigmoidf_(acc[mi][2][r] + bias[1024 + jg]);
            float cc = tanhf(acc[mi][3][r] + bias[1536 + jg]);
            float mg = sigmoidf_(acc[mi][4][r] + bias[2048 + jg]);
            float cold = c_t[(long)jg * B_ + b];
            float rr = ret[jg];
            float cn = f * cold + ii * cc;
            cn = cn * rr + (1.f - rr) * cold;
            cn = mg * cn + (1.f - mg) * cold;
            c_t[(long)jg * B_ + b] = cn;
            __half oh = __float2half(o);
            __half th = __float2half(tanhf(cn));
            ov[r] = *(short*)&oh;
            tv[r] = *(short*)&th;
        }
        *(sh4*)&opre[b * H_ + jbase + 4 * q] = ov;
        *(sh4*)&tcn [b * H_ + jbase + 4 * q] = tv;
    }
}

// Single-layer wrapper (boundary steps). grid = 1024 (32 m x 32 n), XCD-grouped.
__global__ __launch_bounds__(256)
void fused_gate_single(const __hip_bfloat16* A0, int lda0, const __hip_bfloat16* A1,
                       int lda1, int ksplit, int K,
                       const __hip_bfloat16* Wp, int ldw,
                       const float* bias, const float* ret, float* c_t,
                       __half* opre, __half* tcn) {
    const int id = blockIdx.x;
    const int xcd = id & 7;
    const int rest = id >> 3;                 // [0,128)
    const int m = xcd * 4 + (rest & 3);
    const int n = (rest >> 2) & 31;
    fused_gate_core(A0, lda0, A1, lda1, ksplit, K, Wp, ldw, bias, ret, c_t,
                    opre, tcn, m, n);
}

// Dual-layer wrapper. grid = 2048: xcd=id&7; rest bits [0:1]=m-sub, [2:6]=n, [7]=z.
__global__ __launch_bounds__(256)
void fused_gate_dual(const __hip_bfloat16* A0a, int lda0a, const __hip_bfloat16* A1a,
                     int lda1a, int ksplita, int Ka,
                     const __hip_bfloat16* Wpa, int ldwa,
                     const float* biasa, const float* reta, float* cta,
                     __half* oprea, __half* tcna,
                     const __hip_bfloat16* A0b, int lda0b, const __hip_bfloat16* A1b,
                     int lda1b, int ksplitb, int Kb,
                     const __hip_bfloat16* Wpb, int ldwb,
                     const float* biasb, const float* retb, float* ctb,
                     __half* opreb, __half* tcnb) {
    const int id = blockIdx.x;
    const int xcd = id & 7;
    const int rest = id >> 3;                 // [0,256)
    const int m = xcd * 4 + (rest & 3);
    const int n = (rest >> 2) & 31;
    const int z = rest >> 7;
    if (z == 0)
        fused_gate_core(A0a, lda0a, A1a, lda1a, ksplita, Ka, Wpa, ldwa,
                        biasa, reta, cta, oprea, tcna, m, n);
    else
        fused_gate_core(A0b, lda0b, A1b, lda1b, ksplitb, Kb, Wpb, ldwb,
                        biasb, retb, ctb, opreb, tcnb, m, n);
}

// ---------------------------------------------------------------------------
// gate_ln: the two LayerNorms (need full-j stats) on f16 o/tanh(c).
// ---------------------------------------------------------------------------
__device__ __forceinline__ void block_reduce2(float& a, float& b, float* red) {
    #pragma unroll
    for (int off = 32; off > 0; off >>= 1) {
        a += __shfl_down(a, off, 64);
        b += __shfl_down(b, off, 64);
    }
    int lane = threadIdx.x & 63, w = threadIdx.x >> 6;
    if (lane == 0) { red[w] = a; red[8 + w] = b; }
    __syncthreads();
    a = red[0] + red[1] + red[2] + red[3];
    b = red[8] + red[9] + red[10] + red[11];
    __syncthreads();
}

__device__ __forceinline__
void gate_ln_body(const __half* __restrict__ opre,
                  const __half* __restrict__ tcn,
                  const float* __restrict__ elg, const float* __restrict__ elb,
                  const float* __restrict__ lng, const float* __restrict__ lnb,
                  __hip_bfloat16* __restrict__ hout, long hstride, int b) {
    const int tid = threadIdx.x;
    __shared__ float red[16];

    float o_[2], t_[2];
    float s = 0.f, s2 = 0.f;
    #pragma unroll
    for (int u = 0; u < 2; ++u) {
        int j = tid + u * 256;
        float o = __half2float(opre[(long)b * H_ + j]);
        float t = __half2float(tcn[(long)b * H_ + j]);
        o_[u] = o; t_[u] = t;
        s += o; s2 += o * o;
    }
    block_reduce2(s, s2, red);
    float mean = s * (1.f / H_);
    float var = s2 * (1.f / H_) - mean * mean;
    float rstd = rsqrtf(var + EPSF);

    float val[2];
    float s3 = 0.f, s4 = 0.f;
    #pragma unroll
    for (int u = 0; u < 2; ++u) {
        int j = tid + u * 256;
        float on = (o_[u] - mean) * rstd * elg[j] + elb[j];
        float v = sigmoidf_(on) * t_[u];
        val[u] = v; s3 += v; s4 += v * v;
    }
    block_reduce2(s3, s4, red);
    float mean2 = s3 * (1.f / H_);
    float var2 = s4 * (1.f / H_) - mean2 * mean2;
    float rstd2 = rsqrtf(var2 + EPSF);
    #pragma unroll
    for (int u = 0; u < 2; ++u) {
        int j = tid + u * 256;
        float h = (val[u] - mean2) * rstd2 * lng[j] + lnb[j];
        hout[(long)b * hstride + j] = __float2bfloat16(h);
    }
}

__global__ __launch_bounds__(256)
void gate_ln(const __half* __restrict__ opre,
             const __half* __restrict__ tcn,
             const float* __restrict__ elg, const float* __restrict__ elb,
             const float* __restrict__ lng, const float* __restrict__ lnb,
             __hip_bfloat16* __restrict__ hout, long hstride) {
    gate_ln_body(opre, tcn, elg, elb, lng, lnb, hout, hstride, blockIdx.x);
}

__global__ __launch_bounds__(256)
void gate_ln_dual(const __half* oa, const __half* ta,
                  const float* elga, const float* elba,
                  const float* lnga, const float* lnba,
                  __hip_bfloat16* houta, long hstridea,
                  const __half* ob, const __half* tb,
                  const float* elgb, const float* elbb,
                  const float* lngb, const float* lnbb,
                  __hip_bfloat16* houtb, long hstrideb) {
    int bid = blockIdx.x;
    bool isB = bid >= B_;
    int b = isB ? bid - B_ : bid;
    gate_ln_body(isB ? ob : oa, isB ? tb : ta,
                 isB ? elgb : elga, isB ? elbb : elba,
                 isB ? lngb : lnga, isB ? lnbb : lnba,
                 isB ? houtb : houta, isB ? hstrideb : hstridea, b);
}

// ---------------------------------------------------------------------------
// R23 fused attention: seq cached in LDS (one HBM pass, both passes read LDS
// instead of phase-2 L2-latency loads), per-head softmax weight table in LDS
// (dedups the 64x-redundant exp per lane). LDS ~32 KB -> 5 blocks/CU.
// ---------------------------------------------------------------------------
__global__ __launch_bounds__(256)
void attn_fused(const __hip_bfloat16* __restrict__ seq,
                const __hip_bfloat16* __restrict__ U,
                __hip_bfloat16* __restrict__ sbar) {
    const int b = blockIdx.x, tid = threadIdx.x;
    const int h = tid >> 6, lane = tid & 63;
    const int c0 = lane * 8;
    __shared__ __hip_bfloat16 ss[TT * H_];   // 30 KB
    __shared__ float ps[NH_ * TT];           // 480 B
    __shared__ float we[NH_ * TT];           // 480 B
    const float scale = 0.08838834764831845f;   // 1/sqrt(128)

    // one async pass: seq row-block -> LDS (linear, wave-uniform + lane*16)
    const __hip_bfloat16* srow = seq + (size_t)b * TT * H_;
    for (int i = tid; i < TT * H_ / 8; i += 256)
        async_load16(srow + i * 8, &ss[i * 8]);

    float uq[8];
    {
        bf16x8 uv = *(const bf16x8*)&U[(size_t)b * (NH_ * H_) + h * H_ + c0];
        for (int j = 0; j < 8; ++j) uq[j] = bf2f(uv[j]);
    }
    __syncthreads();   // drains global_load_lds

    for (int t = 0; t < TT; ++t) {
        bf16x8 sv = *(const bf16x8*)&ss[t * H_ + c0];
        float a = 0.f;
        for (int j = 0; j < 8; ++j) a += uq[j] * bf2f(sv[j]);
        a += __shfl_xor(a, 32);
        a += __shfl_xor(a, 16);
        a += __shfl_xor(a, 8);
        a += __shfl_xor(a, 4);
        a += __shfl_xor(a, 2);
        a += __shfl_xor(a, 1);
        if (lane == 0) ps[h * TT + t] = a * scale;
    }
    __syncthreads();

    float mx = -1e30f;
    for (int t = 0; t < TT; ++t) mx = fmaxf(mx, ps[h * TT + t]);
    float den = 0.f;
    for (int t = 0; t < TT; ++t) den += __expf(ps[h * TT + t] - mx);
    float inv = 1.f / den;
    if (lane < TT) we[h * TT + lane] = __expf(ps[h * TT + lane] - mx) * inv;
    __syncthreads();

    float accv[8];
    for (int j = 0; j < 8; ++j) accv[j] = 0.f;
    for (int t = 0; t < TT; ++t) {
        float w = we[h * TT + t];
        bf16x8 sv = *(const bf16x8*)&ss[t * H_ + c0];
        for (int j = 0; j < 8; ++j) accv[j] += w * bf2f(sv[j]);
    }
    bf16x8 outv;
    for (int j = 0; j < 8; ++j) {
        __hip_bfloat16 hv = __float2bfloat16(accv[j]);
        outv[j] = *(short*)&hv;
    }
    *(bf16x8*)&sbar[(size_t)b * (NH_ * H_) + h * H_ + c0] = outv;
}

// ---------------------------------------------------------------------------
// Head (unchanged).
// ---------------------------------------------------------------------------
__global__ __launch_bounds__(128)
void head_kernel(const float* __restrict__ lat_in,
                 const float* __restrict__ g2, const float* __restrict__ b2,
                 const float* __restrict__ rm2, const float* __restrict__ rv2,
                 const float* __restrict__ ow, const float* __restrict__ ob,
                 float* __restrict__ out) {
    const int b = blockIdx.x, tid = threadIdx.x;
    __shared__ float ls[LAT_];
    float a = lat_in[(long)b * LAT_ + tid];
    ls[tid] = (a - rm2[tid]) * rsqrtf(rv2[tid] + EPSF) * g2[tid] + b2[tid];
    __syncthreads();
    if (tid < OUT_) {
        float acc = ob[tid];
        #pragma unroll 4
        for (int j = 0; j < LAT_; ++j) acc += ls[j] * ow[tid * LAT_ + j];
        out[(long)b * OUT_ + tid] = acc;
    }
}

// ---------------------------------------------------------------------------
extern "C" void kernel_launch(void* const* d_in, const int* in_sizes, int n_in,
                              void* d_out, int out_size, void* d_ws, size_t ws_size,
                              hipStream_t stream) {
    const float* x        = (const float*)d_in[0];
    const float* conv1_w  = (const float*)d_in[1];
    const float* conv1_b  = (const float*)d_in[2];
    const float* bn1_g    = (const float*)d_in[3];
    const float* bn1_b    = (const float*)d_in[4];
    const float* bn1_rm   = (const float*)d_in[5];
    const float* bn1_rv   = (const float*)d_in[6];
    const float* comp_w   = (const float*)d_in[7];
    const float* comp_b   = (const float*)d_in[8];
    const float* proj_w   = (const float*)d_in[9];
    const float* proj_b   = (const float*)d_in[10];
    const float* gates_w  = (const float*)d_in[11];
    const float* gates_b  = (const float*)d_in[12];
    const float* retention= (const float*)d_in[13];
    const float* expln_g  = (const float*)d_in[14];
    const float* expln_b  = (const float*)d_in[15];
    const float* ln_g     = (const float*)d_in[16];
    const float* ln_b     = (const float*)d_in[17];
    const float* attn_in_w  = (const float*)d_in[18];
    const float* attn_in_b  = (const float*)d_in[19];
    const float* attn_out_w = (const float*)d_in[20];
    const float* attn_out_b = (const float*)d_in[21];
    const float* bneck_w  = (const float*)d_in[22];
    const float* bneck_b  = (const float*)d_in[23];
    const float* bn2_g    = (const float*)d_in[24];
    const float* bn2_b    = (const float*)d_in[25];
    const float* bn2_rm   = (const float*)d_in[26];
    const float* bn2_rv   = (const float*)d_in[27];
    const float* out_w    = (const float*)d_in[28];
    const float* out_b    = (const float*)d_in[29];
    float* out = (float*)d_out;

    // ---- workspace layout (~230 MiB) ----
    char* base = (char*)d_ws;
    size_t off = 0;
    auto alloc = [&](size_t nbytes) -> char* {
        char* p = base + off;
        off += (nbytes + 255) & ~(size_t)255;
        return p;
    };
    __hip_bfloat16* seq_bf = (__hip_bfloat16*)alloc((size_t)B_ * TT * H_ * 2);   // 126 MB
    // union (42 MB): scan f16 o/tanh x2 layers (16 MB) / attn U+sbar+wkt+wv
    size_t g_bytes = (size_t)B_ * NGATE_ * 2;                                    // 21 MB
    char* un = alloc(2 * g_bytes);
    __half* opreA = (__half*)un;                                   // 4 MB (layer1)
    __half* tcnA  = (__half*)(un + (size_t)4 * 1024 * 1024);
    __half* opreB = (__half*)(un + (size_t)8 * 1024 * 1024);       // layer0
    __half* tcnB  = (__half*)(un + (size_t)12 * 1024 * 1024);
    __hip_bfloat16* U_bf    = (__hip_bfloat16*)un;                               // attn phase
    __hip_bfloat16* sbar_bf = (__hip_bfloat16*)(un + (size_t)16 * 1024 * 1024);
    __hip_bfloat16* wkt_bf  = (__hip_bfloat16*)(un + (size_t)32 * 1024 * 1024);  // 0.5 MB
    __hip_bfloat16* wv_bf   = (__hip_bfloat16*)(un + (size_t)35 * 1024 * 1024);  // 0.5 MB
    __hip_bfloat16* feat_bf = (__hip_bfloat16*)alloc((size_t)B_ * TT * FEATK * 2); // 15.7 MB
    float*          c0t   = (float*)alloc((size_t)B_ * H_ * 4);   // transposed [j][B]
    float*          c1t   = (float*)alloc((size_t)B_ * H_ * 4);
    __hip_bfloat16* h0_bf = (__hip_bfloat16*)alloc((size_t)B_ * H_ * 2);
    __hip_bfloat16* q_bf  = (__hip_bfloat16*)alloc((size_t)B_ * H_ * 2);  // also fin
    __hip_bfloat16* fin_bf = q_bf;
    __hip_bfloat16* av_bf = (__hip_bfloat16*)alloc((size_t)B_ * H_ * 2);
    float*          lat_f = (float*)alloc((size_t)B_ * LAT_ * 4);
    __hip_bfloat16* w1p_bf = (__hip_bfloat16*)alloc((size_t)NGATE_ * 2 * H_ * 2); // 5.24 MB
    __hip_bfloat16* w0p_bf = (__hip_bfloat16*)alloc((size_t)NGATE_ * K0M * 2);    // 2.95 MB
    float*          bc_f  = (float*)alloc((size_t)NGATE_ * 4);
    __hip_bfloat16* ai_bf = (__hip_bfloat16*)alloc((size_t)H_ * H_ * 2);  // q rows only
    __hip_bfloat16* ao_bf = (__hip_bfloat16*)alloc((size_t)H_ * H_ * 2);
    __hip_bfloat16* bw_bf = (__hip_bfloat16*)alloc((size_t)LAT_ * H_ * 2);
    (void)ws_size; (void)in_sizes; (void)n_in; (void)out_size;

    // ---- weight conversion / composition / permutation + state zeroing ----
    const int WL = 5 * H_ * 2 * H_;
    perm_w1<<<(NGATE_ * 2 * H_) / 256, 256, 0, stream>>>(gates_w + WL, w1p_bf);
    build_w0m<<<NGATE_ / 4, 256, 0, stream>>>(gates_w, proj_w, proj_b, gates_b,
                                              w0p_bf, bc_f);
    cvt_bf16<<<256, 256, 0, stream>>>(attn_in_w, ai_bf, (long)H_ * H_);
    cvt_bf16<<<256, 256, 0, stream>>>(attn_out_w, ao_bf, (long)H_ * H_);
    cvt_bf16<<<64, 256, 0, stream>>>(bneck_w, bw_bf, (long)LAT_ * H_);
    zero_f32<<<2048, 256, 0, stream>>>(c0t, (long)2 * B_ * H_);   // c0t+c1t contiguous

    // ---- front-end: feat only (proj composed into layer0 weights) ----
    frontend_kernel<<<B_, 256, 0, stream>>>(x, conv1_w, conv1_b, bn1_g, bn1_b, bn1_rm,
                                            bn1_rv, comp_w, comp_b, feat_bf);

    // ---- recurrent scan (layer1(t) || layer0(t+1) dual pipeline) ----
    // layer0 @ t=0: K=64 (composed feat cols only; h=0)
    fused_gate_single<<<1024, 256, 0, stream>>>(
        feat_bf, TT * FEATK, (const __hip_bfloat16*)nullptr, 0, FEATK, FEATK,
        w0p_bf, K0M, bc_f, retention, c0t, opreB, tcnB);
    gate_ln<<<B_, 256, 0, stream>>>(opreB, tcnB, expln_g, expln_b,
                                    ln_g, ln_b, h0_bf, H_);

    for (int t = 0; t < TT - 1; ++t) {
        fused_gate_dual<<<2048, 256, 0, stream>>>(
            // z0 = layer1(t): K = t? 1024 : 512 (h1(-1)=0), ksplit 512
            h0_bf, H_, (t == 0) ? (const __hip_bfloat16*)nullptr
                                : seq_bf + (size_t)(t - 1) * H_,
            TT * H_, H_, (t == 0) ? H_ : 2 * H_,
            w1p_bf, 2 * H_, gates_b + NGATE_, retention + H_, c1t, opreA, tcnA,
            // z1 = layer0(t+1): K = 576 (64 composed feat + 512 h), ksplit 64
            feat_bf + (size_t)(t + 1) * FEATK, TT * FEATK, h0_bf, H_, FEATK, K0M,
            w0p_bf, K0M, bc_f, retention, c0t, opreB, tcnB);
        gate_ln_dual<<<2 * B_, 256, 0, stream>>>(
            opreA, tcnA, expln_g + H_, expln_b + H_, ln_g + H_, ln_b + H_,
            seq_bf + (size_t)t * H_, TT * H_,
            opreB, tcnB, expln_g, expln_b, ln_g, ln_b, h0_bf, H_);
    }
    // layer1 @ t=29
    fused_gate_single<<<1024, 256, 0, stream>>>(
        h0_bf, H_, seq_bf + (size_t)(TT - 2) * H_, TT * H_, H_, 2 * H_,
        w1p_bf, 2 * H_, gates_b + NGATE_, retention + H_, c1t, opreA, tcnA);
    gate_ln<<<B_, 256, 0, stream>>>(opreA, tcnA, expln_g + H_, expln_b + H_,
                                    ln_g + H_, ln_b + H_,
                                    seq_bf + (size_t)(TT - 1) * H_, TT * H_);

    // ---- attention: compact per-head weights (exact same sums, 1/4 K) ----
    build_wkt<<<1024, 256, 0, stream>>>(attn_in_w, wkt_bf);
    cvt_bf16<<<1024, 256, 0, stream>>>(attn_in_w + (size_t)(2 * H_) * H_, wv_bf,
                                       (long)H_ * H_);

    // q projection (last timestep) -> bf16
    gemm_bias<1><<<dim3(H_ / 128, B_ / 128), 256, 0, stream>>>(
        seq_bf + (size_t)29 * H_, TT * H_, (const __hip_bfloat16*)nullptr, 0, H_,
        ai_bf, H_, attn_in_b, (void*)q_bf, H_, H_);

    // U_h = q_h @ wkt_h^T  (4 heads, K=128)
    for (int h = 0; h < NH_; ++h)
        gemm_bias<1><<<dim3(4, B_ / 128), 256, 0, stream>>>(
            q_bf + h * DH_, H_, (const __hip_bfloat16*)nullptr, 0, DH_,
            wkt_bf + (size_t)h * 512 * DH_, DH_, (const float*)nullptr,
            (void*)(U_bf + h * 512), 2048, DH_);

    // fused scores/softmax/weighted-sum -> sbar [4096, 2048]
    attn_fused<<<B_, 256, 0, stream>>>(seq_bf, U_bf, sbar_bf);

    // o_h = sbar_h @ Wv_h^T + bv_h  (4 heads, K=512, N=128)
    for (int h = 0; h < NH_; ++h)
        gemm_bias<1><<<dim3(1, B_ / 128), 256, 0, stream>>>(
            sbar_bf + h * 512, 2048, (const __hip_bfloat16*)nullptr, 0, H_,
            wv_bf + (size_t)h * DH_ * H_, H_, attn_in_b + 2 * H_ + h * DH_,
            (void*)(av_bf + h * DH_), H_, H_);

    // attn_out projection -> bf16 fin (aliases q_bf; q fully consumed)
    gemm_bias<1><<<dim3(H_ / 128, B_ / 128), 256, 0, stream>>>(
        av_bf, H_, (const __hip_bfloat16*)nullptr, 0, H_,
        ao_bf, H_, attn_out_b, (void*)fin_bf, H_, H_);

    // ---- bneck GEMM -> latent f32, then bn2+head ----
    gemm_bias<0><<<dim3(LAT_ / 128, B_ / 128), 256, 0, stream>>>(
        fin_bf, H_, (const __hip_bfloat16*)nullptr, 0, H_,
        bw_bf, H_, bneck_b, (void*)lat_f, LAT_, H_);
    head_kernel<<<B_, 128, 0, stream>>>(lat_f, bn2_g, bn2_b, bn2_rm, bn2_rv,
                                        out_w, out_b, out);
}